// Round 6
// baseline (384.821 us; speedup 1.0000x reference)
//
#include <hip/hip_runtime.h>
#include <math.h>
#include <stdint.h>

typedef __attribute__((ext_vector_type(8)))  short   short8;
typedef __attribute__((ext_vector_type(4)))  short   short4v;
typedef __attribute__((ext_vector_type(8)))  __bf16  bf16x8;
typedef __attribute__((ext_vector_type(4)))  float   f32x4;
typedef __attribute__((ext_vector_type(16))) float   f32x16;

__device__ __forceinline__ unsigned short f2b(float f) {
    union { float f; unsigned u; } v; v.f = f;
    unsigned r = v.u + 0x7FFF + ((v.u >> 16) & 1);
    return (unsigned short)(r >> 16);
}

__device__ __forceinline__ f32x4 mfma_bf16(bf16x8 a, bf16x8 b, f32x4 c) {
    return __builtin_amdgcn_mfma_f32_16x16x32_bf16(a, b, c, 0, 0, 0);
}

__device__ __forceinline__ f32x16 mfma32(bf16x8 a, bf16x8 b, f32x16 c) {
    return __builtin_amdgcn_mfma_f32_32x32x16_bf16(a, b, c, 0, 0, 0);
}

__device__ __forceinline__ unsigned cvt_pk_bf16(float lo, float hi) {
    unsigned r;
    asm volatile("v_cvt_pk_bf16_f32 %0, %1, %2" : "=v"(r) : "v"(lo), "v"(hi));
    return r;
}

__device__ __forceinline__ void gload_lds16(const unsigned short* g, unsigned short* l) {
    __builtin_amdgcn_global_load_lds(
        (const __attribute__((address_space(1))) void*)g,
        (__attribute__((address_space(3))) void*)l,
        16, 0, 0);
}

template <int N>
__device__ __forceinline__ void wait_vmcnt() {
    if constexpr (N == 0)       asm volatile("s_waitcnt vmcnt(0)" ::: "memory");
    else if constexpr (N == 6)  asm volatile("s_waitcnt vmcnt(6)" ::: "memory");
    else if constexpr (N == 8)  asm volatile("s_waitcnt vmcnt(8)" ::: "memory");
    else                        static_assert(N == 0 || N == 6 || N == 8, "add vmcnt case");
}

// 0.125 (d_head^-0.5) * log2(e): softmax computed in base-2 (exact rescale)
#define QSCALE 0.18033688011112042592f

// ---------------- weight transpose + f32->bf16 ----------------
__global__ __launch_bounds__(256) void wconv_t(const float* __restrict__ W,
                                               unsigned short* __restrict__ Wt,
                                               int K, int N) {
    __shared__ float tile[32][33];
    int bk = blockIdx.x * 32;
    int bn = blockIdx.y * 32;
    int tx = threadIdx.x & 31, ty = threadIdx.x >> 5;  // 32 x 8
#pragma unroll
    for (int i = 0; i < 4; ++i) {
        int r = ty + i * 8;
        tile[r][tx] = W[(size_t)(bk + r) * N + bn + tx];
    }
    __syncthreads();
#pragma unroll
    for (int i = 0; i < 4; ++i) {
        int r = ty + i * 8;
        Wt[(size_t)(bn + r) * K + bk + tx] = f2b(tile[tx][r]);
    }
}

// ---------------- f32 -> bf16 elementwise (x4) ----------------
__global__ __launch_bounds__(256) void fconv(const float* __restrict__ in,
                                             unsigned short* __restrict__ out, int n4) {
    int i = blockIdx.x * 256 + threadIdx.x;
    if (i >= n4) return;
    f32x4 v = ((const f32x4*)in)[i];
    short4v o;
    o.x = (short)f2b(v.x); o.y = (short)f2b(v.y);
    o.z = (short)f2b(v.z); o.w = (short)f2b(v.w);
    ((short4v*)out)[i] = o;
}

// ---------------- layernorm (C=1024), f32 in -> bf16 out ----------------
__global__ __launch_bounds__(256) void lnorm(const float* __restrict__ x,
                                             const float* __restrict__ g,
                                             const float* __restrict__ bta,
                                             unsigned short* __restrict__ out) {
    int row = blockIdx.x;
    const f32x4* xr = (const f32x4*)(x + (size_t)row * 1024);
    int t = threadIdx.x;
    f32x4 v = xr[t];
    float s  = v.x + v.y + v.z + v.w;
    float s2 = v.x * v.x + v.y * v.y + v.z * v.z + v.w * v.w;
#pragma unroll
    for (int m = 1; m < 64; m <<= 1) {
        s  += __shfl_xor(s, m);
        s2 += __shfl_xor(s2, m);
    }
    __shared__ float rs[8];
    int w = t >> 6;
    if ((t & 63) == 0) { rs[w] = s; rs[4 + w] = s2; }
    __syncthreads();
    s  = rs[0] + rs[1] + rs[2] + rs[3];
    s2 = rs[4] + rs[5] + rs[6] + rs[7];
    float mean = s * (1.0f / 1024.0f);
    float var  = s2 * (1.0f / 1024.0f) - mean * mean;
    float rstd = rsqrtf(var + 1e-5f);
    f32x4 gv = ((const f32x4*)g)[t];
    f32x4 bv = ((const f32x4*)bta)[t];
    short4v o;
    o.x = (short)f2b((v.x - mean) * rstd * gv.x + bv.x);
    o.y = (short)f2b((v.y - mean) * rstd * gv.y + bv.y);
    o.z = (short)f2b((v.z - mean) * rstd * gv.z + bv.z);
    o.w = (short)f2b((v.w - mean) * rstd * gv.w + bv.w);
    ((short4v*)(out + (size_t)row * 1024))[t] = o;
}

// ---------------- pipelined GEMM: A[M,K] x Bt[N,K] -> C[M,N], BK=64 ----------------
template <int WM, int WN, int MI, int NI, int EPI, bool SCQ>
__global__ __launch_bounds__(WM * WN * 64, 2)
void gemm8(const unsigned short* __restrict__ A,
           const unsigned short* __restrict__ Bt,
           void* __restrict__ C,
           const float* __restrict__ bias,
           const float* __restrict__ resid,
           int M, int N, int K, int scale_cols) {
    constexpr int BM = WM * MI * 16;
    constexpr int BN = WN * NI * 16;
    constexpr int THREADS = WM * WN * 64;
    constexpr int ROWS = THREADS / 8;          // rows per stage instr
    constexpr int IA = BM / ROWS;              // stage instrs for A
    constexpr int IB = BN / ROWS;

    // bijective XCD swizzle (all grids are multiples of 8), m-major per XCD
    const int nwg = gridDim.x;
    const int nby = N / BN;
    int flat = blockIdx.x;
    int wk = (flat & 7) * (nwg >> 3) + (flat >> 3);
    const int m0 = (wk / nby) * BM;
    const int n0 = (wk % nby) * BN;

    __shared__ unsigned short As[2][BM * 64];
    __shared__ unsigned short Bs[2][BN * 64];

    const int tid  = threadIdx.x;
    const int lane = tid & 63;
    const int wid  = tid >> 6;
    const int wm = wid / WN, wn = wid % WN;
    const int l15 = lane & 15, q4 = lane >> 4, xw = lane & 7;

    const int sr = tid >> 3;                    // stage row within group
    const int sg = (tid & 7) ^ (sr & 7);        // swizzled source granule

    const unsigned short* ag = A  + (size_t)(m0 + sr) * K + sg * 8;
    const unsigned short* bg = Bt + (size_t)(n0 + sr) * K + sg * 8;

    f32x4 acc[MI][NI] = {};

    auto STAGE = [&](int d, int t) {
        const int k0 = t * 64;
#pragma unroll
        for (int i = 0; i < IA; ++i)
            gload_lds16(ag + (size_t)(i * ROWS) * K + k0, &As[d][i * ROWS * 64 + tid * 8]);
#pragma unroll
        for (int i = 0; i < IB; ++i)
            gload_lds16(bg + (size_t)(i * ROWS) * K + k0, &Bs[d][i * ROWS * 64 + tid * 8]);
    };

    const int NT = K >> 6;
    STAGE(0, 0);

    for (int t = 0; t < NT; ++t) {
        const int c = t & 1;
        if (t + 1 < NT) STAGE(c ^ 1, t + 1);
        __builtin_amdgcn_sched_barrier(0);
        if (t + 1 < NT) wait_vmcnt<IA + IB>();
        else            wait_vmcnt<0>();
        __builtin_amdgcn_s_barrier();
        __builtin_amdgcn_sched_barrier(0);
#pragma unroll
        for (int h = 0; h < 2; ++h) {
            bf16x8 a[MI], b[NI];
            const int gsl = h * 4 + q4;         // granule before swizzle
#pragma unroll
            for (int mi = 0; mi < MI; ++mi)
                a[mi] = *(const bf16x8*)&As[c][(wm * MI * 16 + mi * 16 + l15) * 64 + ((gsl ^ xw) << 3)];
#pragma unroll
            for (int ni = 0; ni < NI; ++ni)
                b[ni] = *(const bf16x8*)&Bs[c][(wn * NI * 16 + ni * 16 + l15) * 64 + ((gsl ^ xw) << 3)];
            __builtin_amdgcn_s_setprio(1);
#pragma unroll
            for (int mi = 0; mi < MI; ++mi)
#pragma unroll
                for (int ni = 0; ni < NI; ++ni)
                    acc[mi][ni] = mfma_bf16(a[mi], b[ni], acc[mi][ni]);
            __builtin_amdgcn_s_setprio(0);
        }
        __builtin_amdgcn_sched_barrier(0);
        __builtin_amdgcn_s_barrier();
    }

    // epilogue
    const int rb = m0 + wm * MI * 16 + q4 * 4;
    const int cb = n0 + wn * NI * 16 + l15;
    float bv[NI];
    if (EPI >= 1) {
#pragma unroll
        for (int ni = 0; ni < NI; ++ni) bv[ni] = bias[cb + ni * 16];
    }
#pragma unroll
    for (int mi = 0; mi < MI; ++mi) {
#pragma unroll
        for (int r = 0; r < 4; ++r) {
            const int row = rb + mi * 16 + r;
#pragma unroll
            for (int ni = 0; ni < NI; ++ni) {
                const int col = cb + ni * 16;
                float v = acc[mi][ni][r];
                if (EPI == 0) {
                    if (SCQ && col < scale_cols) v *= QSCALE;
                    ((unsigned short*)C)[(size_t)row * N + col] = f2b(v);
                } else if (EPI == 1) {
                    v += bv[ni];
                    v = 0.5f * v * (1.0f + erff(v * 0.70710678118f));
                    ((unsigned short*)C)[(size_t)row * N + col] = f2b(v);
                } else {
                    v += bv[ni] + resid[(size_t)row * N + col];
                    ((float*)C)[(size_t)row * N + col] = v;
                }
            }
        }
    }
}

// ---------------- V transpose: [b,n, col_off + h*64 + d] -> Vt[bh][d][n] ----------------
__global__ __launch_bounds__(256) void vtrans(const unsigned short* __restrict__ src,
                                              unsigned short* __restrict__ dst,
                                              int src_stride, int col_off) {
    int n0 = blockIdx.x * 64;
    int bh = blockIdx.y;
    int b = bh >> 4, h = bh & 15;
    __shared__ unsigned short t[64][65];
    int tx = threadIdx.x & 63, ty = threadIdx.x >> 6;  // 64 x 4
    const unsigned short* s = src + (size_t)(b * 2048 + n0) * src_stride + col_off + h * 64;
#pragma unroll
    for (int i = 0; i < 16; ++i) {
        int n = ty * 16 + i;
        t[n][tx] = s[(size_t)n * src_stride + tx];
    }
    __syncthreads();
    unsigned short* d = dst + (size_t)bh * 64 * 2048 + n0;
#pragma unroll
    for (int i = 0; i < 16; ++i) {
        int dd = ty * 16 + i;
        d[(size_t)dd * 2048 + tx] = t[tx][dd];
    }
}

// ---------------- flash attention v3: swapped-operand 32x32, granule-major LDS ----------------
// 2 waves/block, 64 q-rows/block, grid 1024 (XCD-clustered bh). K stored in LDS as
// [d-granule g][k] (8 x 1024B), V^T as [n-granule g][d]: global_load_lds writes lane->
// entry (per-lane scattered GLOBAL rows, linear LDS dest), fragment ds_reads become
// base(l31*16B + l5*1KB) + immediate offsets -> conflict-free, no addr VALU.
// Counted-vmcnt two-barrier pipeline (T3/T4); tree reductions for max/sum.
__global__ __launch_bounds__(128) void attn(const unsigned short* __restrict__ Q, int q_stride, int q_off,
                                            const unsigned short* __restrict__ Kp, int k_stride, int k_off,
                                            const unsigned short* __restrict__ Vt,
                                            const float* __restrict__ res,
                                            float* __restrict__ out) {
    // 1024 blocks: xcd = bid&7 owns bh in {4*xcd .. 4*xcd+3} (2MB K/V, L2-resident)
    const int bid = blockIdx.x;
    const int slot = bid >> 3;                 // 0..127
    const int bh = (bid & 7) * 4 + (slot >> 5);
    const int qt = slot & 31;
    const int b = bh >> 4, h = bh & 15;
    const int lane = threadIdx.x & 63, w = threadIdx.x >> 6;  // w in {0,1}
    const int l31 = lane & 31, l5 = lane >> 5;

    __shared__ unsigned short lds[2][8192];    // [buf][ K: 0..4095 | V: 4096..8191 ] elems

    const int q0 = qt * 64 + w * 32;

    // Q fragments (B-operand): col q = l31, d = i*16 + l5*8 + j
    const unsigned short* qp = Q + (size_t)(b * 2048 + q0 + l31) * q_stride + q_off + h * 64 + l5 * 8;
    bf16x8 qf[4];
#pragma unroll
    for (int i = 0; i < 4; ++i) qf[i] = *(const bf16x8*)&qp[i * 16];

    const unsigned short* kg = Kp + (size_t)(b * 2048) * k_stride + k_off + h * 64;
    const unsigned short* vg = Vt + (size_t)bh * 64 * 2048;

    f32x16 oacc[2] = {};
    float m = -1e30f, l = 0.f;

    // stage: wave w covers granules w*4..w*4+3 for both K and V (8 instrs/wave)
    auto STAGE = [&](int d, int t) {
        const int n0 = t * 64;
#pragma unroll
        for (int j = 0; j < 4; ++j) {
            const int g = w * 4 + j;
            gload_lds16(kg + (size_t)(n0 + lane) * k_stride + g * 8, &lds[d][g * 512]);
            gload_lds16(vg + (size_t)lane * 2048 + n0 + g * 8,       &lds[d][4096 + g * 512]);
        }
    };

    STAGE(0, 0);
    asm volatile("s_waitcnt vmcnt(0)" ::: "memory");
    __builtin_amdgcn_s_barrier();

    for (int t = 0; t < 32; ++t) {
        const int cur = t & 1;
        if (t + 1 < 32) STAGE(cur ^ 1, t + 1);
        __builtin_amdgcn_sched_barrier(0);
        if (t + 1 < 32) wait_vmcnt<8>();
        else            wait_vmcnt<0>();
        __builtin_amdgcn_s_barrier();
        __builtin_amdgcn_sched_barrier(0);

        const unsigned short* Kc = &lds[cur][0];
        const unsigned short* Vc = &lds[cur][4096];

        // K fragments (A-operand): k-row = ks*32 + l31, d-granule = i*2 + l5
        bf16x8 kf[2][4];
#pragma unroll
        for (int ks = 0; ks < 2; ++ks)
#pragma unroll
            for (int i = 0; i < 4; ++i)
                kf[ks][i] = *(const bf16x8*)&Kc[(i * 2 + l5) * 512 + ks * 256 + l31 * 8];

        f32x16 s0 = {}, s1 = {};
        __builtin_amdgcn_s_setprio(1);
#pragma unroll
        for (int i = 0; i < 4; ++i) s0 = mfma32(kf[0][i], qf[i], s0);
#pragma unroll
        for (int i = 0; i < 4; ++i) s1 = mfma32(kf[1][i], qf[i], s1);
        __builtin_amdgcn_s_setprio(0);

        // V fragments (A-operand): d-row = dh*32 + l31, n-granule = c*2 + l5
        bf16x8 vf[2][4];
#pragma unroll
        for (int dh = 0; dh < 2; ++dh)
#pragma unroll
            for (int c = 0; c < 4; ++c)
                vf[dh][c] = *(const bf16x8*)&Vc[(c * 2 + l5) * 512 + dh * 256 + l31 * 8];

        // online softmax (base-2, q lane-local), tree reductions
        float tr[16];
#pragma unroll
        for (int r = 0; r < 16; ++r) tr[r] = fmaxf(s0[r], s1[r]);
#pragma unroll
        for (int off = 8; off >= 1; off >>= 1)
#pragma unroll
            for (int r = 0; r < off; ++r) tr[r] = fmaxf(tr[r], tr[r + off]);
        float mx = fmaxf(tr[0], __shfl_xor(tr[0], 32));
        if (!__all(mx - m <= 8.f)) {  // defer-max (T13): P bounded by 2^8
            float mnew = fmaxf(m, mx);
            float al = __builtin_amdgcn_exp2f(m - mnew);
            m = mnew;
            l *= al;
#pragma unroll
            for (int dh = 0; dh < 2; ++dh)
#pragma unroll
                for (int r = 0; r < 16; ++r) oacc[dh][r] *= al;
        }
        float p0[16], p1[16];
#pragma unroll
        for (int r = 0; r < 16; ++r) p0[r] = __builtin_amdgcn_exp2f(s0[r] - m);
#pragma unroll
        for (int r = 0; r < 16; ++r) p1[r] = __builtin_amdgcn_exp2f(s1[r] - m);
        float sm[16];
#pragma unroll
        for (int r = 0; r < 16; ++r) sm[r] = p0[r] + p1[r];
#pragma unroll
        for (int off = 8; off >= 1; off >>= 1)
#pragma unroll
            for (int r = 0; r < off; ++r) sm[r] += sm[r + off];
        l += sm[0] + __shfl_xor(sm[0], 32);

        // P^T -> B-operand fragments via cvt_pk + permlane32_swap (T12)
        bf16x8 pf[4];
#pragma unroll
        for (int half = 0; half < 2; ++half) {
            const float* p = half ? p1 : p0;
#pragma unroll
            for (int c = 0; c < 2; ++c) {
                unsigned a0 = cvt_pk_bf16(p[8 * c + 0], p[8 * c + 1]);
                unsigned a1 = cvt_pk_bf16(p[8 * c + 4], p[8 * c + 5]);
                unsigned b0 = cvt_pk_bf16(p[8 * c + 2], p[8 * c + 3]);
                unsigned b1 = cvt_pk_bf16(p[8 * c + 6], p[8 * c + 7]);
                asm volatile("v_permlane32_swap_b32 %0, %1" : "+v"(a0), "+v"(a1));
                asm volatile("v_permlane32_swap_b32 %0, %1" : "+v"(b0), "+v"(b1));
                union { unsigned u[4]; bf16x8 v; } pu;
                pu.u[0] = a0; pu.u[1] = b0; pu.u[2] = a1; pu.u[3] = b1;
                pf[half * 2 + c] = pu.v;
            }
        }

        // O^T += V^T · P^T
        __builtin_amdgcn_s_setprio(1);
#pragma unroll
        for (int dh = 0; dh < 2; ++dh)
#pragma unroll
            for (int c = 0; c < 4; ++c)
                oacc[dh] = mfma32(vf[dh][c], pf[c], oacc[dh]);
        __builtin_amdgcn_s_setprio(0);

        __builtin_amdgcn_s_barrier();   // protect buf cur from next iter's STAGE
    }

    // epilogue: O/l + residual.  d_local = (reg&3) + 8*(reg>>2) + 4*l5
    const float inv = 1.0f / l;
    const size_t rowoff = (size_t)(b * 2048 + q0 + l31) * 1024 + h * 64;
#pragma unroll
    for (int dh = 0; dh < 2; ++dh) {
#pragma unroll
        for (int g = 0; g < 4; ++g) {
            const int col = dh * 32 + g * 8 + l5 * 4;
            f32x4 rv = *(const f32x4*)&res[rowoff + col];
            f32x4 ov;
#pragma unroll
            for (int r = 0; r < 4; ++r) ov[r] = oacc[dh][g * 4 + r] * inv + rv[r];
            *(f32x4*)&out[rowoff + col] = ov;
        }
    }
}

// ---------------- host ----------------
extern "C" void kernel_launch(void* const* d_in, const int* in_sizes, int n_in,
                              void* d_out, int out_size, void* d_ws, size_t ws_size,
                              hipStream_t stream) {
    const float* x      = (const float*)d_in[0];
    const float* feat   = (const float*)d_in[1];
    const float* norm_g = (const float*)d_in[2];
    const float* norm_b = (const float*)d_in[3];
    const float* W_cq   = (const float*)d_in[4];
    const float* W_ckv  = (const float*)d_in[5];
    const float* W_sqkv = (const float*)d_in[6];
    const float* ffn_g  = (const float*)d_in[7];
    const float* ffn_b  = (const float*)d_in[8];
    const float* W1     = (const float*)d_in[9];
    const float* b1     = (const float*)d_in[10];
    const float* W2     = (const float*)d_in[11];
    const float* b2     = (const float*)d_in[12];
    float* out = (float*)d_out;

    char* ws = (char*)d_ws;
    unsigned short* wq_t   = (unsigned short*)(ws + (size_t)(0u)   * (1u << 20));  // 2MB
    unsigned short* wkv_t  = (unsigned short*)(ws + (size_t)(2u)   * (1u << 20));  // 1.5MB
    unsigned short* wqkv_t = (unsigned short*)(ws + (size_t)(4u)   * (1u << 20));  // 6MB
    unsigned short* w1_t   = (unsigned short*)(ws + (size_t)(10u)  * (1u << 20));  // 8MB
    unsigned short* w2_t   = (unsigned short*)(ws + (size_t)(18u)  * (1u << 20));  // 8MB
    unsigned short* featb  = (unsigned short*)(ws + (size_t)(26u)  * (1u << 20));  // 3MB
    unsigned short* t0     = (unsigned short*)(ws + (size_t)(29u)  * (1u << 20));  // 8MB
    float*          cross  = (float*)        (ws + (size_t)(37u)  * (1u << 20));   // 16MB
    unsigned short* qb     = (unsigned short*)(ws + (size_t)(53u)  * (1u << 20));  // 8MB
    unsigned short* kvb    = (unsigned short*)(ws + (size_t)(61u)  * (1u << 20));  // 16MB
    unsigned short* qkvb   = (unsigned short*)(ws + (size_t)(77u)  * (1u << 20));  // 24MB
    unsigned short* vtb    = (unsigned short*)(ws + (size_t)(101u) * (1u << 20));  // 8MB
    unsigned short* h1     = (unsigned short*)(ws + (size_t)(53u)  * (1u << 20));  // 32MB (aliases q/kv/qkv, dead by FFN)

    // weights -> bf16 transposed [N,K]
    wconv_t<<<dim3(1024 / 32, 1024 / 32), 256, 0, stream>>>(W_cq,   wq_t,   1024, 1024);
    wconv_t<<<dim3(384 / 32,  2048 / 32), 256, 0, stream>>>(W_ckv,  wkv_t,  384,  2048);
    wconv_t<<<dim3(1024 / 32, 3072 / 32), 256, 0, stream>>>(W_sqkv, wqkv_t, 1024, 3072);
    wconv_t<<<dim3(1024 / 32, 4096 / 32), 256, 0, stream>>>(W1,     w1_t,   1024, 4096);
    wconv_t<<<dim3(4096 / 32, 1024 / 32), 256, 0, stream>>>(W2,     w2_t,   4096, 1024);
    fconv<<<dim3((4096 * 384 / 4) / 256), 256, 0, stream>>>(feat, featb, 4096 * 384 / 4);

    // ---- cross attention ----
    lnorm<<<4096, 256, 0, stream>>>(x, norm_g, norm_b, t0);
    // q: 4096x1024 @ K=1024, 128x64 tiles -> 512 blocks (2/CU)
    gemm8<2, 2, 4, 2, 0, true ><<<512, 256, 0, stream>>>(t0,    wq_t,  qb,  nullptr, nullptr, 4096, 1024, 1024, 1024);
    // kv: 4096x2048 @ K=384, 128^2 tiles -> 512 blocks (2/CU)
    gemm8<2, 2, 4, 4, 0, false><<<512, 256, 0, stream>>>(featb, wkv_t, kvb, nullptr, nullptr, 4096, 2048, 384,  0);
    vtrans<<<dim3(32, 32), 256, 0, stream>>>(kvb, vtb, 2048, 1024);
    attn<<<1024, 128, 0, stream>>>(qb, 1024, 0, kvb, 2048, 0, vtb, x, cross);

    // ---- self attention ----
    lnorm<<<4096, 256, 0, stream>>>(cross, norm_g, norm_b, t0);
    // qkv: 4096x3072 @ K=1024, 128x64 tiles -> 1536 blocks (3/CU, 2 rounds)
    gemm8<2, 2, 4, 2, 0, true ><<<1536, 256, 0, stream>>>(t0, wqkv_t, qkvb, nullptr, nullptr, 4096, 3072, 1024, 1024);
    vtrans<<<dim3(32, 32), 256, 0, stream>>>(qkvb, vtb, 3072, 2048);
    attn<<<1024, 128, 0, stream>>>(qkvb, 3072, 0, qkvb, 3072, 1024, vtb, cross, out);

    // ---- FFN ----
    lnorm<<<4096, 256, 0, stream>>>(out, ffn_g, ffn_b, t0);
    // W1: 4096x4096 @ K=1024, 128^2 tiles -> 1024 blocks (2/CU, 2 rounds), GELU epilogue
    gemm8<2, 2, 4, 4, 1, false><<<1024, 256, 0, stream>>>(t0, w1_t, h1, b1, nullptr, 4096, 4096, 1024, 0);
    // W2: 4096x1024 @ K=4096, 128x64 tiles -> 512 blocks (2/CU), bias+residual f32 epilogue
    gemm8<2, 2, 4, 2, 2, false><<<512, 256, 0, stream>>>(h1, w2_t, out, b2, (const float*)out, 4096, 1024, 4096, 0);
}

// Round 7
// 354.033 us; speedup vs baseline: 1.0870x; 1.0870x over previous
//
#include <hip/hip_runtime.h>
#include <math.h>
#include <stdint.h>

typedef __attribute__((ext_vector_type(8)))  short   short8;
typedef __attribute__((ext_vector_type(4)))  short   short4v;
typedef __attribute__((ext_vector_type(8)))  __bf16  bf16x8;
typedef __attribute__((ext_vector_type(4)))  float   f32x4;
typedef __attribute__((ext_vector_type(16))) float   f32x16;

__device__ __forceinline__ unsigned short f2b(float f) {
    union { float f; unsigned u; } v; v.f = f;
    unsigned r = v.u + 0x7FFF + ((v.u >> 16) & 1);
    return (unsigned short)(r >> 16);
}

__device__ __forceinline__ f32x4 mfma_bf16(bf16x8 a, bf16x8 b, f32x4 c) {
    return __builtin_amdgcn_mfma_f32_16x16x32_bf16(a, b, c, 0, 0, 0);
}

__device__ __forceinline__ f32x16 mfma32(bf16x8 a, bf16x8 b, f32x16 c) {
    return __builtin_amdgcn_mfma_f32_32x32x16_bf16(a, b, c, 0, 0, 0);
}

__device__ __forceinline__ unsigned cvt_pk_bf16(float lo, float hi) {
    unsigned r;
    asm volatile("v_cvt_pk_bf16_f32 %0, %1, %2" : "=v"(r) : "v"(lo), "v"(hi));
    return r;
}

__device__ __forceinline__ void gload_lds16(const unsigned short* g, unsigned short* l) {
    __builtin_amdgcn_global_load_lds(
        (const __attribute__((address_space(1))) void*)g,
        (__attribute__((address_space(3))) void*)l,
        16, 0, 0);
}

template <int N>
__device__ __forceinline__ void wait_vmcnt() {
    if constexpr (N == 0)       asm volatile("s_waitcnt vmcnt(0)" ::: "memory");
    else if constexpr (N == 4)  asm volatile("s_waitcnt vmcnt(4)" ::: "memory");
    else if constexpr (N == 6)  asm volatile("s_waitcnt vmcnt(6)" ::: "memory");
    else if constexpr (N == 8)  asm volatile("s_waitcnt vmcnt(8)" ::: "memory");
    else                        static_assert(N == 0 || N == 4 || N == 6 || N == 8, "add vmcnt case");
}

// 0.125 (d_head^-0.5) * log2(e): softmax computed in base-2 (exact rescale)
#define QSCALE 0.18033688011112042592f

// ---------------- weight transpose + f32->bf16 ----------------
__global__ __launch_bounds__(256) void wconv_t(const float* __restrict__ W,
                                               unsigned short* __restrict__ Wt,
                                               int K, int N) {
    __shared__ float tile[32][33];
    int bk = blockIdx.x * 32;
    int bn = blockIdx.y * 32;
    int tx = threadIdx.x & 31, ty = threadIdx.x >> 5;  // 32 x 8
#pragma unroll
    for (int i = 0; i < 4; ++i) {
        int r = ty + i * 8;
        tile[r][tx] = W[(size_t)(bk + r) * N + bn + tx];
    }
    __syncthreads();
#pragma unroll
    for (int i = 0; i < 4; ++i) {
        int r = ty + i * 8;
        Wt[(size_t)(bn + r) * K + bk + tx] = f2b(tile[tx][r]);
    }
}

// ---------------- f32 -> bf16 elementwise (x4) ----------------
__global__ __launch_bounds__(256) void fconv(const float* __restrict__ in,
                                             unsigned short* __restrict__ out, int n4) {
    int i = blockIdx.x * 256 + threadIdx.x;
    if (i >= n4) return;
    f32x4 v = ((const f32x4*)in)[i];
    short4v o;
    o.x = (short)f2b(v.x); o.y = (short)f2b(v.y);
    o.z = (short)f2b(v.z); o.w = (short)f2b(v.w);
    ((short4v*)out)[i] = o;
}

// ---------------- layernorm (C=1024), f32 in -> bf16 out ----------------
__global__ __launch_bounds__(256) void lnorm(const float* __restrict__ x,
                                             const float* __restrict__ g,
                                             const float* __restrict__ bta,
                                             unsigned short* __restrict__ out) {
    int row = blockIdx.x;
    const f32x4* xr = (const f32x4*)(x + (size_t)row * 1024);
    int t = threadIdx.x;
    f32x4 v = xr[t];
    float s  = v.x + v.y + v.z + v.w;
    float s2 = v.x * v.x + v.y * v.y + v.z * v.z + v.w * v.w;
#pragma unroll
    for (int m = 1; m < 64; m <<= 1) {
        s  += __shfl_xor(s, m);
        s2 += __shfl_xor(s2, m);
    }
    __shared__ float rs[8];
    int w = t >> 6;
    if ((t & 63) == 0) { rs[w] = s; rs[4 + w] = s2; }
    __syncthreads();
    s  = rs[0] + rs[1] + rs[2] + rs[3];
    s2 = rs[4] + rs[5] + rs[6] + rs[7];
    float mean = s * (1.0f / 1024.0f);
    float var  = s2 * (1.0f / 1024.0f) - mean * mean;
    float rstd = rsqrtf(var + 1e-5f);
    f32x4 gv = ((const f32x4*)g)[t];
    f32x4 bv = ((const f32x4*)bta)[t];
    short4v o;
    o.x = (short)f2b((v.x - mean) * rstd * gv.x + bv.x);
    o.y = (short)f2b((v.y - mean) * rstd * gv.y + bv.y);
    o.z = (short)f2b((v.z - mean) * rstd * gv.z + bv.z);
    o.w = (short)f2b((v.w - mean) * rstd * gv.w + bv.w);
    ((short4v*)(out + (size_t)row * 1024))[t] = o;
}

// ---------------- pipelined GEMM: A[M,K] x Bt[N,K] -> C[M,N], BK=64 ----------------
template <int WM, int WN, int MI, int NI, int EPI, bool SCQ>
__global__ __launch_bounds__(WM * WN * 64, 2)
void gemm8(const unsigned short* __restrict__ A,
           const unsigned short* __restrict__ Bt,
           void* __restrict__ C,
           const float* __restrict__ bias,
           const float* __restrict__ resid,
           int M, int N, int K, int scale_cols) {
    constexpr int BM = WM * MI * 16;
    constexpr int BN = WN * NI * 16;
    constexpr int THREADS = WM * WN * 64;
    constexpr int ROWS = THREADS / 8;          // rows per stage instr
    constexpr int IA = BM / ROWS;              // stage instrs for A
    constexpr int IB = BN / ROWS;

    // bijective XCD swizzle (all grids are multiples of 8), m-major per XCD
    const int nwg = gridDim.x;
    const int nby = N / BN;
    int flat = blockIdx.x;
    int wk = (flat & 7) * (nwg >> 3) + (flat >> 3);
    const int m0 = (wk / nby) * BM;
    const int n0 = (wk % nby) * BN;

    __shared__ unsigned short As[2][BM * 64];
    __shared__ unsigned short Bs[2][BN * 64];

    const int tid  = threadIdx.x;
    const int lane = tid & 63;
    const int wid  = tid >> 6;
    const int wm = wid / WN, wn = wid % WN;
    const int l15 = lane & 15, q4 = lane >> 4, xw = lane & 7;

    const int sr = tid >> 3;                    // stage row within group
    const int sg = (tid & 7) ^ (sr & 7);        // swizzled source granule

    const unsigned short* ag = A  + (size_t)(m0 + sr) * K + sg * 8;
    const unsigned short* bg = Bt + (size_t)(n0 + sr) * K + sg * 8;

    f32x4 acc[MI][NI] = {};

    auto STAGE = [&](int d, int t) {
        const int k0 = t * 64;
#pragma unroll
        for (int i = 0; i < IA; ++i)
            gload_lds16(ag + (size_t)(i * ROWS) * K + k0, &As[d][i * ROWS * 64 + tid * 8]);
#pragma unroll
        for (int i = 0; i < IB; ++i)
            gload_lds16(bg + (size_t)(i * ROWS) * K + k0, &Bs[d][i * ROWS * 64 + tid * 8]);
    };

    const int NT = K >> 6;
    STAGE(0, 0);

    for (int t = 0; t < NT; ++t) {
        const int c = t & 1;
        if (t + 1 < NT) STAGE(c ^ 1, t + 1);
        __builtin_amdgcn_sched_barrier(0);
        if (t + 1 < NT) wait_vmcnt<IA + IB>();
        else            wait_vmcnt<0>();
        __builtin_amdgcn_s_barrier();
        __builtin_amdgcn_sched_barrier(0);
#pragma unroll
        for (int h = 0; h < 2; ++h) {
            bf16x8 a[MI], b[NI];
            const int gsl = h * 4 + q4;         // granule before swizzle
#pragma unroll
            for (int mi = 0; mi < MI; ++mi)
                a[mi] = *(const bf16x8*)&As[c][(wm * MI * 16 + mi * 16 + l15) * 64 + ((gsl ^ xw) << 3)];
#pragma unroll
            for (int ni = 0; ni < NI; ++ni)
                b[ni] = *(const bf16x8*)&Bs[c][(wn * NI * 16 + ni * 16 + l15) * 64 + ((gsl ^ xw) << 3)];
            __builtin_amdgcn_s_setprio(1);
#pragma unroll
            for (int mi = 0; mi < MI; ++mi)
#pragma unroll
                for (int ni = 0; ni < NI; ++ni)
                    acc[mi][ni] = mfma_bf16(a[mi], b[ni], acc[mi][ni]);
            __builtin_amdgcn_s_setprio(0);
        }
        __builtin_amdgcn_sched_barrier(0);
        __builtin_amdgcn_s_barrier();
    }

    // epilogue
    const int rb = m0 + wm * MI * 16 + q4 * 4;
    const int cb = n0 + wn * NI * 16 + l15;
    float bv[NI];
    if (EPI >= 1) {
#pragma unroll
        for (int ni = 0; ni < NI; ++ni) bv[ni] = bias[cb + ni * 16];
    }
#pragma unroll
    for (int mi = 0; mi < MI; ++mi) {
#pragma unroll
        for (int r = 0; r < 4; ++r) {
            const int row = rb + mi * 16 + r;
#pragma unroll
            for (int ni = 0; ni < NI; ++ni) {
                const int col = cb + ni * 16;
                float v = acc[mi][ni][r];
                if (EPI == 0) {
                    if (SCQ && col < scale_cols) v *= QSCALE;
                    ((unsigned short*)C)[(size_t)row * N + col] = f2b(v);
                } else if (EPI == 1) {
                    v += bv[ni];
                    v = 0.5f * v * (1.0f + erff(v * 0.70710678118f));
                    ((unsigned short*)C)[(size_t)row * N + col] = f2b(v);
                } else {
                    v += bv[ni] + resid[(size_t)row * N + col];
                    ((float*)C)[(size_t)row * N + col] = v;
                }
            }
        }
    }
}

// ---------------- V transpose: [b,n, col_off + h*64 + d] -> Vt[bh][d][n] ----------------
__global__ __launch_bounds__(256) void vtrans(const unsigned short* __restrict__ src,
                                              unsigned short* __restrict__ dst,
                                              int src_stride, int col_off) {
    int n0 = blockIdx.x * 64;
    int bh = blockIdx.y;
    int b = bh >> 4, h = bh & 15;
    __shared__ unsigned short t[64][65];
    int tx = threadIdx.x & 63, ty = threadIdx.x >> 6;  // 64 x 4
    const unsigned short* s = src + (size_t)(b * 2048 + n0) * src_stride + col_off + h * 64;
#pragma unroll
    for (int i = 0; i < 16; ++i) {
        int n = ty * 16 + i;
        t[n][tx] = s[(size_t)n * src_stride + tx];
    }
    __syncthreads();
    unsigned short* d = dst + (size_t)bh * 64 * 2048 + n0;
#pragma unroll
    for (int i = 0; i < 16; ++i) {
        int dd = ty * 16 + i;
        d[(size_t)dd * 2048 + tx] = t[tx][dd];
    }
}

// ---------------- flash attention v4: swapped-operand 32x32, depth-2 pipeline ----------------
// Round-5 structure (coalesced row-major K/V staging via global_load_lds, XOR-swizzle
// involution on source-col + read addr, 4 waves x 32 q) + 3-buffer depth-2 prefetch:
// steady state waits vmcnt(8) (= 2 tiles x 4 loads/wave in flight), never drains to 0
// mid-loop. Tree reductions for max/sum; T12 cvt_pk+permlane32 P->fragments; T13 defer-max.
__global__ __launch_bounds__(256) void attn(const unsigned short* __restrict__ Q, int q_stride, int q_off,
                                            const unsigned short* __restrict__ Kp, int k_stride, int k_off,
                                            const unsigned short* __restrict__ Vt,
                                            const float* __restrict__ res,
                                            float* __restrict__ out) {
    // 512 blocks; XCD = bid%8 owns 4 bh values -> K/V (2MB) L2-resident per XCD
    const int bid = blockIdx.x;
    const int slot = bid >> 3;
    const int bh = (bid & 7) * 4 + (slot >> 4);
    const int qt = slot & 15;
    const int b = bh >> 4, h = bh & 15;
    const int lane = threadIdx.x & 63, w = threadIdx.x >> 6;
    const int l31 = lane & 31, l5 = lane >> 5;

    __shared__ unsigned short Ks[3][64 * 64];
    __shared__ unsigned short Vs[3][64 * 64];

    const int q0 = qt * 128 + w * 32;

    // Q fragments (B-operand): col q = l31, d = i*16 + l5*8 + j
    const unsigned short* qp = Q + (size_t)(b * 2048 + q0 + l31) * q_stride + q_off + h * 64 + l5 * 8;
    bf16x8 qf[4];
#pragma unroll
    for (int i = 0; i < 4; ++i) qf[i] = *(const bf16x8*)&qp[i * 16];

    const unsigned short* kg = Kp + (size_t)(b * 2048) * k_stride + k_off + h * 64;
    const unsigned short* vg = Vt + (size_t)bh * 64 * 2048;

    const int sgrow = lane >> 3;                          // row within 8-row group
    const int sgcol = (((lane & 7) ^ sgrow) << 3);        // element col (16B granule XOR)

    f32x16 oacc[2] = {};
    float m = -1e30f, l = 0.f;

    const int kxor = (l31 & 7) << 3;   // read-side XOR (elements)

    // stage one 64x64 K tile + 64x64 V^T tile; 4 loads per wave (2 K + 2 V)
    auto STAGE = [&](int d, int t) {
        const int n0s = t * 64;
#pragma unroll
        for (int t8 = 0; t8 < 2; ++t8) {
            const int rb = w * 16 + t8 * 8;
            gload_lds16(kg + (size_t)(n0s + rb + sgrow) * k_stride + sgcol, &Ks[d][rb * 64]);
            gload_lds16(vg + (size_t)(rb + sgrow) * 2048 + n0s + sgcol,     &Vs[d][rb * 64]);
        }
    };

    // ---- prologue: stage tiles 0 and 1 (depth 2) ----
    STAGE(0, 0);
    STAGE(1, 1);

    for (int t = 0; t < 32; ++t) {
        const int cur = t % 3;
        if (t + 2 < 32) STAGE((t + 2) % 3, t + 2);
        __builtin_amdgcn_sched_barrier(0);
        if (t + 2 < 32)      wait_vmcnt<8>();   // tiles t+1, t+2 stay in flight
        else if (t + 1 < 32) wait_vmcnt<4>();   // tile t+1 in flight
        else                 wait_vmcnt<0>();
        __builtin_amdgcn_s_barrier();
        __builtin_amdgcn_sched_barrier(0);

        const unsigned short* Kc = &Ks[cur][0];
        const unsigned short* Vc = &Vs[cur][0];

        // K fragments (A-operand): row k = ks*32 + l31, d = (i*16 + l5*8) ^ kxor
        bf16x8 kf[2][4];
#pragma unroll
        for (int ks = 0; ks < 2; ++ks)
#pragma unroll
            for (int i = 0; i < 4; ++i)
                kf[ks][i] = *(const bf16x8*)&Kc[(ks * 32 + l31) * 64 + ((i * 16 + l5 * 8) ^ kxor)];

        f32x16 s0 = {}, s1 = {};
        __builtin_amdgcn_s_setprio(1);
#pragma unroll
        for (int i = 0; i < 4; ++i) s0 = mfma32(kf[0][i], qf[i], s0);
#pragma unroll
        for (int i = 0; i < 4; ++i) s1 = mfma32(kf[1][i], qf[i], s1);
        __builtin_amdgcn_s_setprio(0);

        // V fragments (A-operand): row d = dh*32 + l31, k = (c*16 + l5*8) ^ kxor
        bf16x8 vf[2][4];
#pragma unroll
        for (int dh = 0; dh < 2; ++dh)
#pragma unroll
            for (int c = 0; c < 4; ++c)
                vf[dh][c] = *(const bf16x8*)&Vc[(dh * 32 + l31) * 64 + ((c * 16 + l5 * 8) ^ kxor)];

        // online softmax (base-2, q lane-local), tree reductions
        float tr[16];
#pragma unroll
        for (int r = 0; r < 16; ++r) tr[r] = fmaxf(s0[r], s1[r]);
#pragma unroll
        for (int off = 8; off >= 1; off >>= 1)
#pragma unroll
            for (int r = 0; r < off; ++r) tr[r] = fmaxf(tr[r], tr[r + off]);
        float mx = fmaxf(tr[0], __shfl_xor(tr[0], 32));
        if (!__all(mx - m <= 8.f)) {  // defer-max (T13): P bounded by 2^8
            float mnew = fmaxf(m, mx);
            float al = __builtin_amdgcn_exp2f(m - mnew);
            m = mnew;
            l *= al;
#pragma unroll
            for (int dh = 0; dh < 2; ++dh)
#pragma unroll
                for (int r = 0; r < 16; ++r) oacc[dh][r] *= al;
        }
        float p0[16], p1[16];
#pragma unroll
        for (int r = 0; r < 16; ++r) p0[r] = __builtin_amdgcn_exp2f(s0[r] - m);
#pragma unroll
        for (int r = 0; r < 16; ++r) p1[r] = __builtin_amdgcn_exp2f(s1[r] - m);
        float sm[16];
#pragma unroll
        for (int r = 0; r < 16; ++r) sm[r] = p0[r] + p1[r];
#pragma unroll
        for (int off = 8; off >= 1; off >>= 1)
#pragma unroll
            for (int r = 0; r < off; ++r) sm[r] += sm[r + off];
        l += sm[0] + __shfl_xor(sm[0], 32);

        // P^T -> B-operand fragments via cvt_pk + permlane32_swap (T12)
        bf16x8 pf[4];
#pragma unroll
        for (int half = 0; half < 2; ++half) {
            const float* p = half ? p1 : p0;
#pragma unroll
            for (int c = 0; c < 2; ++c) {
                unsigned a0 = cvt_pk_bf16(p[8 * c + 0], p[8 * c + 1]);
                unsigned a1 = cvt_pk_bf16(p[8 * c + 4], p[8 * c + 5]);
                unsigned b0 = cvt_pk_bf16(p[8 * c + 2], p[8 * c + 3]);
                unsigned b1 = cvt_pk_bf16(p[8 * c + 6], p[8 * c + 7]);
                asm volatile("v_permlane32_swap_b32 %0, %1" : "+v"(a0), "+v"(a1));
                asm volatile("v_permlane32_swap_b32 %0, %1" : "+v"(b0), "+v"(b1));
                union { unsigned u[4]; bf16x8 v; } pu;
                pu.u[0] = a0; pu.u[1] = b0; pu.u[2] = a1; pu.u[3] = b1;
                pf[half * 2 + c] = pu.v;
            }
        }

        // O^T += V^T · P^T
        __builtin_amdgcn_s_setprio(1);
#pragma unroll
        for (int dh = 0; dh < 2; ++dh)
#pragma unroll
            for (int c = 0; c < 4; ++c)
                oacc[dh] = mfma32(vf[dh][c], pf[c], oacc[dh]);
        __builtin_amdgcn_s_setprio(0);

        __builtin_amdgcn_s_barrier();   // all waves done reading buf cur before it is re-staged
    }

    // epilogue: O/l + residual.  d_local = (reg&3) + 8*(reg>>2) + 4*l5
    const float inv = 1.0f / l;
    const size_t rowoff = (size_t)(b * 2048 + q0 + l31) * 1024 + h * 64;
#pragma unroll
    for (int dh = 0; dh < 2; ++dh) {
#pragma unroll
        for (int g = 0; g < 4; ++g) {
            const int col = dh * 32 + g * 8 + l5 * 4;
            f32x4 rv = *(const f32x4*)&res[rowoff + col];
            f32x4 ov;
#pragma unroll
            for (int r = 0; r < 4; ++r) ov[r] = oacc[dh][g * 4 + r] * inv + rv[r];
            *(f32x4*)&out[rowoff + col] = ov;
        }
    }
}

// ---------------- host ----------------
extern "C" void kernel_launch(void* const* d_in, const int* in_sizes, int n_in,
                              void* d_out, int out_size, void* d_ws, size_t ws_size,
                              hipStream_t stream) {
    const float* x      = (const float*)d_in[0];
    const float* feat   = (const float*)d_in[1];
    const float* norm_g = (const float*)d_in[2];
    const float* norm_b = (const float*)d_in[3];
    const float* W_cq   = (const float*)d_in[4];
    const float* W_ckv  = (const float*)d_in[5];
    const float* W_sqkv = (const float*)d_in[6];
    const float* ffn_g  = (const float*)d_in[7];
    const float* ffn_b  = (const float*)d_in[8];
    const float* W1     = (const float*)d_in[9];
    const float* b1     = (const float*)d_in[10];
    const float* W2     = (const float*)d_in[11];
    const float* b2     = (const float*)d_in[12];
    float* out = (float*)d_out;

    char* ws = (char*)d_ws;
    unsigned short* wq_t   = (unsigned short*)(ws + (size_t)(0u)   * (1u << 20));  // 2MB
    unsigned short* wkv_t  = (unsigned short*)(ws + (size_t)(2u)   * (1u << 20));  // 1.5MB
    unsigned short* wqkv_t = (unsigned short*)(ws + (size_t)(4u)   * (1u << 20));  // 6MB
    unsigned short* w1_t   = (unsigned short*)(ws + (size_t)(10u)  * (1u << 20));  // 8MB
    unsigned short* w2_t   = (unsigned short*)(ws + (size_t)(18u)  * (1u << 20));  // 8MB
    unsigned short* featb  = (unsigned short*)(ws + (size_t)(26u)  * (1u << 20));  // 3MB
    unsigned short* t0     = (unsigned short*)(ws + (size_t)(29u)  * (1u << 20));  // 8MB
    float*          cross  = (float*)        (ws + (size_t)(37u)  * (1u << 20));   // 16MB
    unsigned short* qb     = (unsigned short*)(ws + (size_t)(53u)  * (1u << 20));  // 8MB
    unsigned short* kvb    = (unsigned short*)(ws + (size_t)(61u)  * (1u << 20));  // 16MB
    unsigned short* qkvb   = (unsigned short*)(ws + (size_t)(77u)  * (1u << 20));  // 24MB
    unsigned short* vtb    = (unsigned short*)(ws + (size_t)(101u) * (1u << 20));  // 8MB
    unsigned short* h1     = (unsigned short*)(ws + (size_t)(53u)  * (1u << 20));  // 32MB (aliases q/kv/qkv, dead by FFN)

    // weights -> bf16 transposed [N,K]
    wconv_t<<<dim3(1024 / 32, 1024 / 32), 256, 0, stream>>>(W_cq,   wq_t,   1024, 1024);
    wconv_t<<<dim3(384 / 32,  2048 / 32), 256, 0, stream>>>(W_ckv,  wkv_t,  384,  2048);
    wconv_t<<<dim3(1024 / 32, 3072 / 32), 256, 0, stream>>>(W_sqkv, wqkv_t, 1024, 3072);
    wconv_t<<<dim3(1024 / 32, 4096 / 32), 256, 0, stream>>>(W1,     w1_t,   1024, 4096);
    wconv_t<<<dim3(4096 / 32, 1024 / 32), 256, 0, stream>>>(W2,     w2_t,   4096, 1024);
    fconv<<<dim3((4096 * 384 / 4) / 256), 256, 0, stream>>>(feat, featb, 4096 * 384 / 4);

    // ---- cross attention ----
    lnorm<<<4096, 256, 0, stream>>>(x, norm_g, norm_b, t0);
    // q: 4096x1024 @ K=1024, 128x64 tiles -> 512 blocks (2/CU)
    gemm8<2, 2, 4, 2, 0, true ><<<512, 256, 0, stream>>>(t0,    wq_t,  qb,  nullptr, nullptr, 4096, 1024, 1024, 1024);
    // kv: 4096x2048 @ K=384, 128^2 tiles -> 512 blocks (2/CU)
    gemm8<2, 2, 4, 4, 0, false><<<512, 256, 0, stream>>>(featb, wkv_t, kvb, nullptr, nullptr, 4096, 2048, 384,  0);
    vtrans<<<dim3(32, 32), 256, 0, stream>>>(kvb, vtb, 2048, 1024);
    attn<<<512, 256, 0, stream>>>(qb, 1024, 0, kvb, 2048, 0, vtb, x, cross);

    // ---- self attention ----
    lnorm<<<4096, 256, 0, stream>>>(cross, norm_g, norm_b, t0);
    // qkv: 4096x3072 @ K=1024, 128x64 tiles -> 1536 blocks (3/CU, 2 rounds)
    gemm8<2, 2, 4, 2, 0, true ><<<1536, 256, 0, stream>>>(t0, wqkv_t, qkvb, nullptr, nullptr, 4096, 3072, 1024, 1024);
    vtrans<<<dim3(32, 32), 256, 0, stream>>>(qkvb, vtb, 3072, 2048);
    attn<<<512, 256, 0, stream>>>(qkvb, 3072, 0, qkvb, 3072, 1024, vtb, cross, out);

    // ---- FFN ----
    lnorm<<<4096, 256, 0, stream>>>(out, ffn_g, ffn_b, t0);
    // W1: 4096x4096 @ K=1024, 128^2 tiles -> 1024 blocks (2/CU, 2 rounds), GELU epilogue
    gemm8<2, 2, 4, 4, 1, false><<<1024, 256, 0, stream>>>(t0, w1_t, h1, b1, nullptr, 4096, 4096, 1024, 0);
    // W2: 4096x1024 @ K=4096, 128x64 tiles -> 512 blocks (2/CU), bias+residual f32 epilogue
    gemm8<2, 2, 4, 2, 2, false><<<512, 256, 0, stream>>>(h1, w2_t, out, b2, (const float*)out, 4096, 1024, 4096, 0);
}

// Round 8
// 348.007 us; speedup vs baseline: 1.1058x; 1.0173x over previous
//
#include <hip/hip_runtime.h>
#include <math.h>
#include <stdint.h>

typedef __attribute__((ext_vector_type(8)))  short   short8;
typedef __attribute__((ext_vector_type(4)))  short   short4v;
typedef __attribute__((ext_vector_type(8)))  __bf16  bf16x8;
typedef __attribute__((ext_vector_type(4)))  float   f32x4;
typedef __attribute__((ext_vector_type(16))) float   f32x16;

__device__ __forceinline__ unsigned short f2b(float f) {
    union { float f; unsigned u; } v; v.f = f;
    unsigned r = v.u + 0x7FFF + ((v.u >> 16) & 1);
    return (unsigned short)(r >> 16);
}

__device__ __forceinline__ f32x4 mfma_bf16(bf16x8 a, bf16x8 b, f32x4 c) {
    return __builtin_amdgcn_mfma_f32_16x16x32_bf16(a, b, c, 0, 0, 0);
}

__device__ __forceinline__ f32x16 mfma32(bf16x8 a, bf16x8 b, f32x16 c) {
    return __builtin_amdgcn_mfma_f32_32x32x16_bf16(a, b, c, 0, 0, 0);
}

__device__ __forceinline__ unsigned cvt_pk_bf16(float lo, float hi) {
    unsigned r;
    asm volatile("v_cvt_pk_bf16_f32 %0, %1, %2" : "=v"(r) : "v"(lo), "v"(hi));
    return r;
}

__device__ __forceinline__ void gload_lds16(const unsigned short* g, unsigned short* l) {
    __builtin_amdgcn_global_load_lds(
        (const __attribute__((address_space(1))) void*)g,
        (__attribute__((address_space(3))) void*)l,
        16, 0, 0);
}

template <int N>
__device__ __forceinline__ void wait_vmcnt() {
    if constexpr (N == 0)       asm volatile("s_waitcnt vmcnt(0)" ::: "memory");
    else if constexpr (N == 4)  asm volatile("s_waitcnt vmcnt(4)" ::: "memory");
    else if constexpr (N == 6)  asm volatile("s_waitcnt vmcnt(6)" ::: "memory");
    else if constexpr (N == 8)  asm volatile("s_waitcnt vmcnt(8)" ::: "memory");
    else                        static_assert(N == 0 || N == 4 || N == 6 || N == 8, "add vmcnt case");
}

// 0.125 (d_head^-0.5) * log2(e): softmax computed in base-2 (exact rescale)
#define QSCALE 0.18033688011112042592f

// ---------------- weight transpose + f32->bf16 ----------------
__global__ __launch_bounds__(256) void wconv_t(const float* __restrict__ W,
                                               unsigned short* __restrict__ Wt,
                                               int K, int N) {
    __shared__ float tile[32][33];
    int bk = blockIdx.x * 32;
    int bn = blockIdx.y * 32;
    int tx = threadIdx.x & 31, ty = threadIdx.x >> 5;  // 32 x 8
#pragma unroll
    for (int i = 0; i < 4; ++i) {
        int r = ty + i * 8;
        tile[r][tx] = W[(size_t)(bk + r) * N + bn + tx];
    }
    __syncthreads();
#pragma unroll
    for (int i = 0; i < 4; ++i) {
        int r = ty + i * 8;
        Wt[(size_t)(bn + r) * K + bk + tx] = f2b(tile[tx][r]);
    }
}

// ---------------- f32 -> bf16 elementwise (x4) ----------------
__global__ __launch_bounds__(256) void fconv(const float* __restrict__ in,
                                             unsigned short* __restrict__ out, int n4) {
    int i = blockIdx.x * 256 + threadIdx.x;
    if (i >= n4) return;
    f32x4 v = ((const f32x4*)in)[i];
    short4v o;
    o.x = (short)f2b(v.x); o.y = (short)f2b(v.y);
    o.z = (short)f2b(v.z); o.w = (short)f2b(v.w);
    ((short4v*)out)[i] = o;
}

// ---------------- layernorm (C=1024), f32 in -> bf16 out ----------------
__global__ __launch_bounds__(256) void lnorm(const float* __restrict__ x,
                                             const float* __restrict__ g,
                                             const float* __restrict__ bta,
                                             unsigned short* __restrict__ out) {
    int row = blockIdx.x;
    const f32x4* xr = (const f32x4*)(x + (size_t)row * 1024);
    int t = threadIdx.x;
    f32x4 v = xr[t];
    float s  = v.x + v.y + v.z + v.w;
    float s2 = v.x * v.x + v.y * v.y + v.z * v.z + v.w * v.w;
#pragma unroll
    for (int m = 1; m < 64; m <<= 1) {
        s  += __shfl_xor(s, m);
        s2 += __shfl_xor(s2, m);
    }
    __shared__ float rs[8];
    int w = t >> 6;
    if ((t & 63) == 0) { rs[w] = s; rs[4 + w] = s2; }
    __syncthreads();
    s  = rs[0] + rs[1] + rs[2] + rs[3];
    s2 = rs[4] + rs[5] + rs[6] + rs[7];
    float mean = s * (1.0f / 1024.0f);
    float var  = s2 * (1.0f / 1024.0f) - mean * mean;
    float rstd = rsqrtf(var + 1e-5f);
    f32x4 gv = ((const f32x4*)g)[t];
    f32x4 bv = ((const f32x4*)bta)[t];
    short4v o;
    o.x = (short)f2b((v.x - mean) * rstd * gv.x + bv.x);
    o.y = (short)f2b((v.y - mean) * rstd * gv.y + bv.y);
    o.z = (short)f2b((v.z - mean) * rstd * gv.z + bv.z);
    o.w = (short)f2b((v.w - mean) * rstd * gv.w + bv.w);
    ((short4v*)(out + (size_t)row * 1024))[t] = o;
}

// ---------------- pipelined GEMM: A[M,K] x Bt[N,K] -> C[M,N], BK=64 ----------------
template <int WM, int WN, int MI, int NI, int EPI, bool SCQ>
__global__ __launch_bounds__(WM * WN * 64, 2)
void gemm8(const unsigned short* __restrict__ A,
           const unsigned short* __restrict__ Bt,
           void* __restrict__ C,
           const float* __restrict__ bias,
           const float* __restrict__ resid,
           int M, int N, int K, int scale_cols) {
    constexpr int BM = WM * MI * 16;
    constexpr int BN = WN * NI * 16;
    constexpr int THREADS = WM * WN * 64;
    constexpr int ROWS = THREADS / 8;          // rows per stage instr
    constexpr int IA = BM / ROWS;              // stage instrs for A
    constexpr int IB = BN / ROWS;

    // bijective XCD swizzle (all grids are multiples of 8), m-major per XCD
    const int nwg = gridDim.x;
    const int nby = N / BN;
    int flat = blockIdx.x;
    int wk = (flat & 7) * (nwg >> 3) + (flat >> 3);
    const int m0 = (wk / nby) * BM;
    const int n0 = (wk % nby) * BN;

    __shared__ unsigned short As[2][BM * 64];
    __shared__ unsigned short Bs[2][BN * 64];

    const int tid  = threadIdx.x;
    const int lane = tid & 63;
    const int wid  = tid >> 6;
    const int wm = wid / WN, wn = wid % WN;
    const int l15 = lane & 15, q4 = lane >> 4, xw = lane & 7;

    const int sr = tid >> 3;                    // stage row within group
    const int sg = (tid & 7) ^ (sr & 7);        // swizzled source granule

    const unsigned short* ag = A  + (size_t)(m0 + sr) * K + sg * 8;
    const unsigned short* bg = Bt + (size_t)(n0 + sr) * K + sg * 8;

    f32x4 acc[MI][NI] = {};

    auto STAGE = [&](int d, int t) {
        const int k0 = t * 64;
#pragma unroll
        for (int i = 0; i < IA; ++i)
            gload_lds16(ag + (size_t)(i * ROWS) * K + k0, &As[d][i * ROWS * 64 + tid * 8]);
#pragma unroll
        for (int i = 0; i < IB; ++i)
            gload_lds16(bg + (size_t)(i * ROWS) * K + k0, &Bs[d][i * ROWS * 64 + tid * 8]);
    };

    const int NT = K >> 6;
    STAGE(0, 0);

    for (int t = 0; t < NT; ++t) {
        const int c = t & 1;
        if (t + 1 < NT) STAGE(c ^ 1, t + 1);
        __builtin_amdgcn_sched_barrier(0);
        if (t + 1 < NT) wait_vmcnt<IA + IB>();
        else            wait_vmcnt<0>();
        __builtin_amdgcn_s_barrier();
        __builtin_amdgcn_sched_barrier(0);
#pragma unroll
        for (int h = 0; h < 2; ++h) {
            bf16x8 a[MI], b[NI];
            const int gsl = h * 4 + q4;         // granule before swizzle
#pragma unroll
            for (int mi = 0; mi < MI; ++mi)
                a[mi] = *(const bf16x8*)&As[c][(wm * MI * 16 + mi * 16 + l15) * 64 + ((gsl ^ xw) << 3)];
#pragma unroll
            for (int ni = 0; ni < NI; ++ni)
                b[ni] = *(const bf16x8*)&Bs[c][(wn * NI * 16 + ni * 16 + l15) * 64 + ((gsl ^ xw) << 3)];
            __builtin_amdgcn_s_setprio(1);
#pragma unroll
            for (int mi = 0; mi < MI; ++mi)
#pragma unroll
                for (int ni = 0; ni < NI; ++ni)
                    acc[mi][ni] = mfma_bf16(a[mi], b[ni], acc[mi][ni]);
            __builtin_amdgcn_s_setprio(0);
        }
        __builtin_amdgcn_sched_barrier(0);
        __builtin_amdgcn_s_barrier();
    }

    // epilogue
    const int rb = m0 + wm * MI * 16 + q4 * 4;
    const int cb = n0 + wn * NI * 16 + l15;
    float bv[NI];
    if (EPI >= 1) {
#pragma unroll
        for (int ni = 0; ni < NI; ++ni) bv[ni] = bias[cb + ni * 16];
    }
#pragma unroll
    for (int mi = 0; mi < MI; ++mi) {
#pragma unroll
        for (int r = 0; r < 4; ++r) {
            const int row = rb + mi * 16 + r;
#pragma unroll
            for (int ni = 0; ni < NI; ++ni) {
                const int col = cb + ni * 16;
                float v = acc[mi][ni][r];
                if (EPI == 0) {
                    if (SCQ && col < scale_cols) v *= QSCALE;
                    ((unsigned short*)C)[(size_t)row * N + col] = f2b(v);
                } else if (EPI == 1) {
                    v += bv[ni];
                    v = 0.5f * v * (1.0f + erff(v * 0.70710678118f));
                    ((unsigned short*)C)[(size_t)row * N + col] = f2b(v);
                } else {
                    v += bv[ni] + resid[(size_t)row * N + col];
                    ((float*)C)[(size_t)row * N + col] = v;
                }
            }
        }
    }
}

// ---------------- 8-phase-style 256^2 GEMM (m201 template, 4 phases/K-tile) ----------------
// 8 waves (2x4), per-wave 128x64 output, BK=64, 128KB dbuf LDS. Per phase:
// {ds_read quadrant frags || issue prefetch (3/3/2/0) -> lgkmcnt(0) -> setprio MFMA x16
// -> barrier}. vmcnt(0) only at tile end (last prefetch issued >=1 phase earlier).
template <int EPI, bool SCQ>
__global__ __launch_bounds__(512, 2)
void gemm256(const unsigned short* __restrict__ A,
             const unsigned short* __restrict__ Bt,
             void* __restrict__ C,
             const float* __restrict__ bias,
             const float* __restrict__ resid,
             int M, int N, int K, int scale_cols) {
    const int nby = N / 256;
    const int nwg = gridDim.x;
    int flat = blockIdx.x;
    int wk = (flat & 7) * (nwg >> 3) + (flat >> 3);
    const int m0 = (wk / nby) * 256;
    const int n0 = (wk % nby) * 256;

    __shared__ unsigned short As[2][256 * 64];
    __shared__ unsigned short Bs[2][256 * 64];

    const int tid  = threadIdx.x;
    const int lane = tid & 63;
    const int wid  = tid >> 6;                 // 0..7
    const int wm = wid >> 2, wn = wid & 3;     // 2 x 4 waves
    const int l15 = lane & 15, q4 = lane >> 4, xw = lane & 7;

    const int sr = tid >> 3;                   // 0..63
    const int sg = (tid & 7) ^ (sr & 7);       // swizzled source granule

    const unsigned short* ag = A  + (size_t)(m0 + sr) * K + sg * 8;
    const unsigned short* bg = Bt + (size_t)(n0 + sr) * K + sg * 8;

    f32x4 acc[8][4] = {};

#define SA256(d, t, i) gload_lds16(ag + (size_t)((i) * 64) * K + (t) * 64, &As[d][(i) * 4096 + tid * 8])
#define SB256(d, t, i) gload_lds16(bg + (size_t)((i) * 64) * K + (t) * 64, &Bs[d][(i) * 4096 + tid * 8])

    const int NT = K >> 6;
    // prologue: stage tile 0
#pragma unroll
    for (int i = 0; i < 4; ++i) { SA256(0, 0, i); SB256(0, 0, i); }
    wait_vmcnt<0>();
    __builtin_amdgcn_s_barrier();

    for (int t = 0; t < NT; ++t) {
        const int c = t & 1;
        const bool pf = (t + 1 < NT);
        bf16x8 breg[4];
#pragma unroll
        for (int p = 0; p < 4; ++p) {
            const int h = p >> 1, mh = p & 1;
            const int col = ((h * 4 + q4) ^ xw) << 3;
            if ((p & 1) == 0) {
#pragma unroll
                for (int ni = 0; ni < 4; ++ni)
                    breg[ni] = *(const bf16x8*)&Bs[c][(wn * 64 + ni * 16 + l15) * 64 + col];
            }
            bf16x8 a[4];
#pragma unroll
            for (int mi = 0; mi < 4; ++mi)
                a[mi] = *(const bf16x8*)&As[c][(wm * 128 + mh * 64 + mi * 16 + l15) * 64 + col];
            if (pf) {
                if (p == 0)      { SA256(c ^ 1, t + 1, 0); SB256(c ^ 1, t + 1, 0); SA256(c ^ 1, t + 1, 1); }
                else if (p == 1) { SB256(c ^ 1, t + 1, 1); SA256(c ^ 1, t + 1, 2); SB256(c ^ 1, t + 1, 2); }
                else if (p == 2) { SA256(c ^ 1, t + 1, 3); SB256(c ^ 1, t + 1, 3); }
            }
            __builtin_amdgcn_sched_barrier(0);
            asm volatile("s_waitcnt lgkmcnt(0)" ::: "memory");
            __builtin_amdgcn_sched_barrier(0);
            __builtin_amdgcn_s_setprio(1);
#pragma unroll
            for (int mi = 0; mi < 4; ++mi)
#pragma unroll
                for (int ni = 0; ni < 4; ++ni)
                    acc[mh * 4 + mi][ni] = mfma_bf16(a[mi], breg[ni], acc[mh * 4 + mi][ni]);
            __builtin_amdgcn_s_setprio(0);
            __builtin_amdgcn_sched_barrier(0);
            if (p == 3) wait_vmcnt<0>();   // last prefetch issued in p==2, ~1 phase ago
            __builtin_amdgcn_s_barrier();
        }
    }
#undef SA256
#undef SB256

    // epilogue (MI=8, NI=4)
    const int rb = m0 + wm * 128 + q4 * 4;
    const int cb = n0 + wn * 64 + l15;
    float bv[4];
    if (EPI >= 1) {
#pragma unroll
        for (int ni = 0; ni < 4; ++ni) bv[ni] = bias[cb + ni * 16];
    }
#pragma unroll
    for (int ai = 0; ai < 8; ++ai) {
#pragma unroll
        for (int r = 0; r < 4; ++r) {
            const int row = rb + ai * 16 + r;
#pragma unroll
            for (int ni = 0; ni < 4; ++ni) {
                const int col = cb + ni * 16;
                float v = acc[ai][ni][r];
                if (EPI == 0) {
                    if (SCQ && col < scale_cols) v *= QSCALE;
                    ((unsigned short*)C)[(size_t)row * N + col] = f2b(v);
                } else if (EPI == 1) {
                    v += bv[ni];
                    v = 0.5f * v * (1.0f + erff(v * 0.70710678118f));
                    ((unsigned short*)C)[(size_t)row * N + col] = f2b(v);
                } else {
                    v += bv[ni] + resid[(size_t)row * N + col];
                    ((float*)C)[(size_t)row * N + col] = v;
                }
            }
        }
    }
}

// ---------------- V transpose: [b,n, col_off + h*64 + d] -> Vt[bh][d][n] ----------------
__global__ __launch_bounds__(256) void vtrans(const unsigned short* __restrict__ src,
                                              unsigned short* __restrict__ dst,
                                              int src_stride, int col_off) {
    int n0 = blockIdx.x * 64;
    int bh = blockIdx.y;
    int b = bh >> 4, h = bh & 15;
    __shared__ unsigned short t[64][65];
    int tx = threadIdx.x & 63, ty = threadIdx.x >> 6;  // 64 x 4
    const unsigned short* s = src + (size_t)(b * 2048 + n0) * src_stride + col_off + h * 64;
#pragma unroll
    for (int i = 0; i < 16; ++i) {
        int n = ty * 16 + i;
        t[n][tx] = s[(size_t)n * src_stride + tx];
    }
    __syncthreads();
    unsigned short* d = dst + (size_t)bh * 64 * 2048 + n0;
#pragma unroll
    for (int i = 0; i < 16; ++i) {
        int dd = ty * 16 + i;
        d[(size_t)dd * 2048 + tx] = t[tx][dd];
    }
}

// ---------------- flash attention v5: swapped-operand 32x32, counted depth-1 ----------------
// 2-buffer staging; STAGE(next) -> vmcnt(4) -> barrier -> compute -> plain s_barrier:
// next tile's 4 loads/wave stay in flight under the whole compute phase (no drain).
__global__ __launch_bounds__(256) void attn(const unsigned short* __restrict__ Q, int q_stride, int q_off,
                                            const unsigned short* __restrict__ Kp, int k_stride, int k_off,
                                            const unsigned short* __restrict__ Vt,
                                            const float* __restrict__ res,
                                            float* __restrict__ out) {
    // 512 blocks; XCD = bid%8 owns 4 bh values -> K/V (2MB) L2-resident per XCD
    const int bid = blockIdx.x;
    const int slot = bid >> 3;
    const int bh = (bid & 7) * 4 + (slot >> 4);
    const int qt = slot & 15;
    const int b = bh >> 4, h = bh & 15;
    const int lane = threadIdx.x & 63, w = threadIdx.x >> 6;
    const int l31 = lane & 31, l5 = lane >> 5;

    __shared__ unsigned short Ks[2][64 * 64];
    __shared__ unsigned short Vs[2][64 * 64];

    const int q0 = qt * 128 + w * 32;

    // Q fragments (B-operand): col q = l31, d = i*16 + l5*8 + j
    const unsigned short* qp = Q + (size_t)(b * 2048 + q0 + l31) * q_stride + q_off + h * 64 + l5 * 8;
    bf16x8 qf[4];
#pragma unroll
    for (int i = 0; i < 4; ++i) qf[i] = *(const bf16x8*)&qp[i * 16];

    const unsigned short* kg = Kp + (size_t)(b * 2048) * k_stride + k_off + h * 64;
    const unsigned short* vg = Vt + (size_t)bh * 64 * 2048;

    const int sgrow = lane >> 3;                          // row within 8-row group
    const int sgcol = (((lane & 7) ^ sgrow) << 3);        // element col (16B granule XOR)

    f32x16 oacc[2] = {};
    float m = -1e30f, l = 0.f;

    const int kxor = (l31 & 7) << 3;   // read-side XOR (elements)

    // stage one 64x64 K tile + 64x64 V^T tile; 4 loads per wave (2 K + 2 V)
    auto STAGE = [&](int d, int t) {
        const int n0s = t * 64;
#pragma unroll
        for (int t8 = 0; t8 < 2; ++t8) {
            const int rb = w * 16 + t8 * 8;
            gload_lds16(kg + (size_t)(n0s + rb + sgrow) * k_stride + sgcol, &Ks[d][rb * 64]);
            gload_lds16(vg + (size_t)(rb + sgrow) * 2048 + n0s + sgcol,     &Vs[d][rb * 64]);
        }
    };

    STAGE(0, 0);

    for (int t = 0; t < 32; ++t) {
        const int cur = t & 1;
        if (t + 1 < 32) STAGE(cur ^ 1, t + 1);
        __builtin_amdgcn_sched_barrier(0);
        if (t + 1 < 32) wait_vmcnt<4>();   // wait tile t's 4 loads; t+1's stay in flight
        else            wait_vmcnt<0>();
        __builtin_amdgcn_s_barrier();
        __builtin_amdgcn_sched_barrier(0);

        const unsigned short* Kc = &Ks[cur][0];
        const unsigned short* Vc = &Vs[cur][0];

        // K fragments (A-operand): row k = ks*32 + l31, d = (i*16 + l5*8) ^ kxor
        bf16x8 kf[2][4];
#pragma unroll
        for (int ks = 0; ks < 2; ++ks)
#pragma unroll
            for (int i = 0; i < 4; ++i)
                kf[ks][i] = *(const bf16x8*)&Kc[(ks * 32 + l31) * 64 + ((i * 16 + l5 * 8) ^ kxor)];

        f32x16 s0 = {}, s1 = {};
        __builtin_amdgcn_s_setprio(1);
#pragma unroll
        for (int i = 0; i < 4; ++i) s0 = mfma32(kf[0][i], qf[i], s0);
#pragma unroll
        for (int i = 0; i < 4; ++i) s1 = mfma32(kf[1][i], qf[i], s1);
        __builtin_amdgcn_s_setprio(0);

        // V fragments (A-operand): row d = dh*32 + l31, k = (c*16 + l5*8) ^ kxor
        bf16x8 vf[2][4];
#pragma unroll
        for (int dh = 0; dh < 2; ++dh)
#pragma unroll
            for (int c = 0; c < 4; ++c)
                vf[dh][c] = *(const bf16x8*)&Vc[(dh * 32 + l31) * 64 + ((c * 16 + l5 * 8) ^ kxor)];

        // online softmax (base-2, q lane-local), tree reductions
        float tr[16];
#pragma unroll
        for (int r = 0; r < 16; ++r) tr[r] = fmaxf(s0[r], s1[r]);
#pragma unroll
        for (int off = 8; off >= 1; off >>= 1)
#pragma unroll
            for (int r = 0; r < off; ++r) tr[r] = fmaxf(tr[r], tr[r + off]);
        float mx = fmaxf(tr[0], __shfl_xor(tr[0], 32));
        if (!__all(mx - m <= 8.f)) {  // defer-max (T13): P bounded by 2^8
            float mnew = fmaxf(m, mx);
            float al = __builtin_amdgcn_exp2f(m - mnew);
            m = mnew;
            l *= al;
#pragma unroll
            for (int dh = 0; dh < 2; ++dh)
#pragma unroll
                for (int r = 0; r < 16; ++r) oacc[dh][r] *= al;
        }
        float p0[16], p1[16];
#pragma unroll
        for (int r = 0; r < 16; ++r) p0[r] = __builtin_amdgcn_exp2f(s0[r] - m);
#pragma unroll
        for (int r = 0; r < 16; ++r) p1[r] = __builtin_amdgcn_exp2f(s1[r] - m);
        float sm[16];
#pragma unroll
        for (int r = 0; r < 16; ++r) sm[r] = p0[r] + p1[r];
#pragma unroll
        for (int off = 8; off >= 1; off >>= 1)
#pragma unroll
            for (int r = 0; r < off; ++r) sm[r] += sm[r + off];
        l += sm[0] + __shfl_xor(sm[0], 32);

        // P^T -> B-operand fragments via cvt_pk + permlane32_swap (T12)
        bf16x8 pf[4];
#pragma unroll
        for (int half = 0; half < 2; ++half) {
            const float* p = half ? p1 : p0;
#pragma unroll
            for (int c = 0; c < 2; ++c) {
                unsigned a0 = cvt_pk_bf16(p[8 * c + 0], p[8 * c + 1]);
                unsigned a1 = cvt_pk_bf16(p[8 * c + 4], p[8 * c + 5]);
                unsigned b0 = cvt_pk_bf16(p[8 * c + 2], p[8 * c + 3]);
                unsigned b1 = cvt_pk_bf16(p[8 * c + 6], p[8 * c + 7]);
                asm volatile("v_permlane32_swap_b32 %0, %1" : "+v"(a0), "+v"(a1));
                asm volatile("v_permlane32_swap_b32 %0, %1" : "+v"(b0), "+v"(b1));
                union { unsigned u[4]; bf16x8 v; } pu;
                pu.u[0] = a0; pu.u[1] = b0; pu.u[2] = a1; pu.u[3] = b1;
                pf[half * 2 + c] = pu.v;
            }
        }

        // O^T += V^T · P^T
        __builtin_amdgcn_s_setprio(1);
#pragma unroll
        for (int dh = 0; dh < 2; ++dh)
#pragma unroll
            for (int c = 0; c < 4; ++c)
                oacc[dh] = mfma32(vf[dh][c], pf[c], oacc[dh]);
        __builtin_amdgcn_s_setprio(0);

        __builtin_amdgcn_s_barrier();   // all waves done reading buf cur before re-stage
    }

    // epilogue: O/l + residual.  d_local = (reg&3) + 8*(reg>>2) + 4*l5
    const float inv = 1.0f / l;
    const size_t rowoff = (size_t)(b * 2048 + q0 + l31) * 1024 + h * 64;
#pragma unroll
    for (int dh = 0; dh < 2; ++dh) {
#pragma unroll
        for (int g = 0; g < 4; ++g) {
            const int col = dh * 32 + g * 8 + l5 * 4;
            f32x4 rv = *(const f32x4*)&res[rowoff + col];
            f32x4 ov;
#pragma unroll
            for (int r = 0; r < 4; ++r) ov[r] = oacc[dh][g * 4 + r] * inv + rv[r];
            *(f32x4*)&out[rowoff + col] = ov;
        }
    }
}

// ---------------- host ----------------
extern "C" void kernel_launch(void* const* d_in, const int* in_sizes, int n_in,
                              void* d_out, int out_size, void* d_ws, size_t ws_size,
                              hipStream_t stream) {
    const float* x      = (const float*)d_in[0];
    const float* feat   = (const float*)d_in[1];
    const float* norm_g = (const float*)d_in[2];
    const float* norm_b = (const float*)d_in[3];
    const float* W_cq   = (const float*)d_in[4];
    const float* W_ckv  = (const float*)d_in[5];
    const float* W_sqkv = (const float*)d_in[6];
    const float* ffn_g  = (const float*)d_in[7];
    const float* ffn_b  = (const float*)d_in[8];
    const float* W1     = (const float*)d_in[9];
    const float* b1     = (const float*)d_in[10];
    const float* W2     = (const float*)d_in[11];
    const float* b2     = (const float*)d_in[12];
    float* out = (float*)d_out;

    char* ws = (char*)d_ws;
    unsigned short* wq_t   = (unsigned short*)(ws + (size_t)(0u)   * (1u << 20));  // 2MB
    unsigned short* wkv_t  = (unsigned short*)(ws + (size_t)(2u)   * (1u << 20));  // 1.5MB
    unsigned short* wqkv_t = (unsigned short*)(ws + (size_t)(4u)   * (1u << 20));  // 6MB
    unsigned short* w1_t   = (unsigned short*)(ws + (size_t)(10u)  * (1u << 20));  // 8MB
    unsigned short* w2_t   = (unsigned short*)(ws + (size_t)(18u)  * (1u << 20));  // 8MB
    unsigned short* featb  = (unsigned short*)(ws + (size_t)(26u)  * (1u << 20));  // 3MB
    unsigned short* t0     = (unsigned short*)(ws + (size_t)(29u)  * (1u << 20));  // 8MB
    float*          cross  = (float*)        (ws + (size_t)(37u)  * (1u << 20));   // 16MB
    unsigned short* qb     = (unsigned short*)(ws + (size_t)(53u)  * (1u << 20));  // 8MB
    unsigned short* kvb    = (unsigned short*)(ws + (size_t)(61u)  * (1u << 20));  // 16MB
    unsigned short* qkvb   = (unsigned short*)(ws + (size_t)(77u)  * (1u << 20));  // 24MB
    unsigned short* vtb    = (unsigned short*)(ws + (size_t)(101u) * (1u << 20));  // 8MB
    unsigned short* h1     = (unsigned short*)(ws + (size_t)(53u)  * (1u << 20));  // 32MB (aliases q/kv/qkv, dead by FFN)

    // weights -> bf16 transposed [N,K]
    wconv_t<<<dim3(1024 / 32, 1024 / 32), 256, 0, stream>>>(W_cq,   wq_t,   1024, 1024);
    wconv_t<<<dim3(384 / 32,  2048 / 32), 256, 0, stream>>>(W_ckv,  wkv_t,  384,  2048);
    wconv_t<<<dim3(1024 / 32, 3072 / 32), 256, 0, stream>>>(W_sqkv, wqkv_t, 1024, 3072);
    wconv_t<<<dim3(1024 / 32, 4096 / 32), 256, 0, stream>>>(W1,     w1_t,   1024, 4096);
    wconv_t<<<dim3(4096 / 32, 1024 / 32), 256, 0, stream>>>(W2,     w2_t,   4096, 1024);
    fconv<<<dim3((4096 * 384 / 4) / 256), 256, 0, stream>>>(feat, featb, 4096 * 384 / 4);

    // ---- cross attention ----
    lnorm<<<4096, 256, 0, stream>>>(x, norm_g, norm_b, t0);
    // q: 4096x1024 @ K=1024, 128x64 tiles -> 512 blocks (2/CU)
    gemm8<2, 2, 4, 2, 0, true ><<<512, 256, 0, stream>>>(t0,    wq_t,  qb,  nullptr, nullptr, 4096, 1024, 1024, 1024);
    // kv: 4096x2048 @ K=384, 128^2 tiles -> 512 blocks (2/CU)
    gemm8<2, 2, 4, 4, 0, false><<<512, 256, 0, stream>>>(featb, wkv_t, kvb, nullptr, nullptr, 4096, 2048, 384,  0);
    vtrans<<<dim3(32, 32), 256, 0, stream>>>(kvb, vtb, 2048, 1024);
    attn<<<512, 256, 0, stream>>>(qb, 1024, 0, kvb, 2048, 0, vtb, x, cross);

    // ---- self attention ----
    lnorm<<<4096, 256, 0, stream>>>(cross, norm_g, norm_b, t0);
    // qkv: 4096x3072 @ K=1024, 256^2 8-phase -> 192 blocks
    gemm256<0, true ><<<192, 512, 0, stream>>>(t0, wqkv_t, qkvb, nullptr, nullptr, 4096, 3072, 1024, 1024);
    vtrans<<<dim3(32, 32), 256, 0, stream>>>(qkvb, vtb, 3072, 2048);
    attn<<<512, 256, 0, stream>>>(qkvb, 3072, 0, qkvb, 3072, 1024, vtb, cross, out);

    // ---- FFN ----
    lnorm<<<4096, 256, 0, stream>>>(out, ffn_g, ffn_b, t0);
    // W1: 4096x4096 @ K=1024, 256^2 8-phase -> 256 blocks (1/CU exact), GELU epilogue
    gemm256<1, false><<<256, 512, 0, stream>>>(t0, w1_t, h1, b1, nullptr, 4096, 4096, 1024, 0);
    // W2: 4096x1024 @ K=4096, 128x64 tiles -> 512 blocks (2/CU), bias+residual f32 epilogue
    gemm8<2, 2, 4, 2, 2, false><<<512, 256, 0, stream>>>(h1, w2_t, out, b2, (const float*)out, 4096, 1024, 4096, 0);
}

// Round 9
// 332.247 us; speedup vs baseline: 1.1582x; 1.0474x over previous
//
#include <hip/hip_runtime.h>
#include <math.h>
#include <stdint.h>

typedef __attribute__((ext_vector_type(8)))  short   short8;
typedef __attribute__((ext_vector_type(4)))  short   short4v;
typedef __attribute__((ext_vector_type(8)))  __bf16  bf16x8;
typedef __attribute__((ext_vector_type(4)))  float   f32x4;
typedef __attribute__((ext_vector_type(16))) float   f32x16;

__device__ __forceinline__ unsigned short f2b(float f) {
    union { float f; unsigned u; } v; v.f = f;
    unsigned r = v.u + 0x7FFF + ((v.u >> 16) & 1);
    return (unsigned short)(r >> 16);
}

__device__ __forceinline__ f32x4 mfma_bf16(bf16x8 a, bf16x8 b, f32x4 c) {
    return __builtin_amdgcn_mfma_f32_16x16x32_bf16(a, b, c, 0, 0, 0);
}

__device__ __forceinline__ f32x16 mfma32(bf16x8 a, bf16x8 b, f32x16 c) {
    return __builtin_amdgcn_mfma_f32_32x32x16_bf16(a, b, c, 0, 0, 0);
}

__device__ __forceinline__ unsigned cvt_pk_bf16(float lo, float hi) {
    unsigned r;
    asm volatile("v_cvt_pk_bf16_f32 %0, %1, %2" : "=v"(r) : "v"(lo), "v"(hi));
    return r;
}

__device__ __forceinline__ void gload_lds16(const unsigned short* g, unsigned short* l) {
    __builtin_amdgcn_global_load_lds(
        (const __attribute__((address_space(1))) void*)g,
        (__attribute__((address_space(3))) void*)l,
        16, 0, 0);
}

template <int N>
__device__ __forceinline__ void wait_vmcnt() {
    if constexpr (N == 0)       asm volatile("s_waitcnt vmcnt(0)" ::: "memory");
    else if constexpr (N == 4)  asm volatile("s_waitcnt vmcnt(4)" ::: "memory");
    else if constexpr (N == 6)  asm volatile("s_waitcnt vmcnt(6)" ::: "memory");
    else if constexpr (N == 8)  asm volatile("s_waitcnt vmcnt(8)" ::: "memory");
    else                        static_assert(N == 0 || N == 4 || N == 6 || N == 8, "add vmcnt case");
}

// 0.125 (d_head^-0.5) * log2(e): softmax computed in base-2 (exact rescale)
#define QSCALE 0.18033688011112042592f

// ---------------- weight transpose + f32->bf16 ----------------
__global__ __launch_bounds__(256) void wconv_t(const float* __restrict__ W,
                                               unsigned short* __restrict__ Wt,
                                               int K, int N) {
    __shared__ float tile[32][33];
    int bk = blockIdx.x * 32;
    int bn = blockIdx.y * 32;
    int tx = threadIdx.x & 31, ty = threadIdx.x >> 5;  // 32 x 8
#pragma unroll
    for (int i = 0; i < 4; ++i) {
        int r = ty + i * 8;
        tile[r][tx] = W[(size_t)(bk + r) * N + bn + tx];
    }
    __syncthreads();
#pragma unroll
    for (int i = 0; i < 4; ++i) {
        int r = ty + i * 8;
        Wt[(size_t)(bn + r) * K + bk + tx] = f2b(tile[tx][r]);
    }
}

// ---------------- f32 -> bf16 elementwise (x4) ----------------
__global__ __launch_bounds__(256) void fconv(const float* __restrict__ in,
                                             unsigned short* __restrict__ out, int n4) {
    int i = blockIdx.x * 256 + threadIdx.x;
    if (i >= n4) return;
    f32x4 v = ((const f32x4*)in)[i];
    short4v o;
    o.x = (short)f2b(v.x); o.y = (short)f2b(v.y);
    o.z = (short)f2b(v.z); o.w = (short)f2b(v.w);
    ((short4v*)out)[i] = o;
}

// ---------------- layernorm (C=1024), f32 in -> bf16 out ----------------
__global__ __launch_bounds__(256) void lnorm(const float* __restrict__ x,
                                             const float* __restrict__ g,
                                             const float* __restrict__ bta,
                                             unsigned short* __restrict__ out) {
    int row = blockIdx.x;
    const f32x4* xr = (const f32x4*)(x + (size_t)row * 1024);
    int t = threadIdx.x;
    f32x4 v = xr[t];
    float s  = v.x + v.y + v.z + v.w;
    float s2 = v.x * v.x + v.y * v.y + v.z * v.z + v.w * v.w;
#pragma unroll
    for (int m = 1; m < 64; m <<= 1) {
        s  += __shfl_xor(s, m);
        s2 += __shfl_xor(s2, m);
    }
    __shared__ float rs[8];
    int w = t >> 6;
    if ((t & 63) == 0) { rs[w] = s; rs[4 + w] = s2; }
    __syncthreads();
    s  = rs[0] + rs[1] + rs[2] + rs[3];
    s2 = rs[4] + rs[5] + rs[6] + rs[7];
    float mean = s * (1.0f / 1024.0f);
    float var  = s2 * (1.0f / 1024.0f) - mean * mean;
    float rstd = rsqrtf(var + 1e-5f);
    f32x4 gv = ((const f32x4*)g)[t];
    f32x4 bv = ((const f32x4*)bta)[t];
    short4v o;
    o.x = (short)f2b((v.x - mean) * rstd * gv.x + bv.x);
    o.y = (short)f2b((v.y - mean) * rstd * gv.y + bv.y);
    o.z = (short)f2b((v.z - mean) * rstd * gv.z + bv.z);
    o.w = (short)f2b((v.w - mean) * rstd * gv.w + bv.w);
    ((short4v*)(out + (size_t)row * 1024))[t] = o;
}

// ---------------- pipelined GEMM: A[M,K] x Bt[N,K] -> C[M,N], BK=64 ----------------
template <int WM, int WN, int MI, int NI, int EPI, bool SCQ>
__global__ __launch_bounds__(WM * WN * 64, 2)
void gemm8(const unsigned short* __restrict__ A,
           const unsigned short* __restrict__ Bt,
           void* __restrict__ C,
           const float* __restrict__ bias,
           const float* __restrict__ resid,
           int M, int N, int K, int scale_cols) {
    constexpr int BM = WM * MI * 16;
    constexpr int BN = WN * NI * 16;
    constexpr int THREADS = WM * WN * 64;
    constexpr int ROWS = THREADS / 8;          // rows per stage instr
    constexpr int IA = BM / ROWS;              // stage instrs for A
    constexpr int IB = BN / ROWS;

    // bijective XCD swizzle (all grids are multiples of 8), m-major per XCD
    const int nwg = gridDim.x;
    const int nby = N / BN;
    int flat = blockIdx.x;
    int wk = (flat & 7) * (nwg >> 3) + (flat >> 3);
    const int m0 = (wk / nby) * BM;
    const int n0 = (wk % nby) * BN;

    __shared__ unsigned short As[2][BM * 64];
    __shared__ unsigned short Bs[2][BN * 64];

    const int tid  = threadIdx.x;
    const int lane = tid & 63;
    const int wid  = tid >> 6;
    const int wm = wid / WN, wn = wid % WN;
    const int l15 = lane & 15, q4 = lane >> 4, xw = lane & 7;

    const int sr = tid >> 3;                    // stage row within group
    const int sg = (tid & 7) ^ (sr & 7);        // swizzled source granule

    const unsigned short* ag = A  + (size_t)(m0 + sr) * K + sg * 8;
    const unsigned short* bg = Bt + (size_t)(n0 + sr) * K + sg * 8;

    f32x4 acc[MI][NI] = {};

    auto STAGE = [&](int d, int t) {
        const int k0 = t * 64;
#pragma unroll
        for (int i = 0; i < IA; ++i)
            gload_lds16(ag + (size_t)(i * ROWS) * K + k0, &As[d][i * ROWS * 64 + tid * 8]);
#pragma unroll
        for (int i = 0; i < IB; ++i)
            gload_lds16(bg + (size_t)(i * ROWS) * K + k0, &Bs[d][i * ROWS * 64 + tid * 8]);
    };

    const int NT = K >> 6;
    STAGE(0, 0);

    for (int t = 0; t < NT; ++t) {
        const int c = t & 1;
        if (t + 1 < NT) STAGE(c ^ 1, t + 1);
        __builtin_amdgcn_sched_barrier(0);
        if (t + 1 < NT) wait_vmcnt<IA + IB>();
        else            wait_vmcnt<0>();
        __builtin_amdgcn_s_barrier();
        __builtin_amdgcn_sched_barrier(0);
#pragma unroll
        for (int h = 0; h < 2; ++h) {
            bf16x8 a[MI], b[NI];
            const int gsl = h * 4 + q4;         // granule before swizzle
#pragma unroll
            for (int mi = 0; mi < MI; ++mi)
                a[mi] = *(const bf16x8*)&As[c][(wm * MI * 16 + mi * 16 + l15) * 64 + ((gsl ^ xw) << 3)];
#pragma unroll
            for (int ni = 0; ni < NI; ++ni)
                b[ni] = *(const bf16x8*)&Bs[c][(wn * NI * 16 + ni * 16 + l15) * 64 + ((gsl ^ xw) << 3)];
            __builtin_amdgcn_s_setprio(1);
#pragma unroll
            for (int mi = 0; mi < MI; ++mi)
#pragma unroll
                for (int ni = 0; ni < NI; ++ni)
                    acc[mi][ni] = mfma_bf16(a[mi], b[ni], acc[mi][ni]);
            __builtin_amdgcn_s_setprio(0);
        }
        __builtin_amdgcn_sched_barrier(0);
        __builtin_amdgcn_s_barrier();
    }

    // epilogue
    const int rb = m0 + wm * MI * 16 + q4 * 4;
    const int cb = n0 + wn * NI * 16 + l15;
    float bv[NI];
    if (EPI >= 1) {
#pragma unroll
        for (int ni = 0; ni < NI; ++ni) bv[ni] = bias[cb + ni * 16];
    }
#pragma unroll
    for (int mi = 0; mi < MI; ++mi) {
#pragma unroll
        for (int r = 0; r < 4; ++r) {
            const int row = rb + mi * 16 + r;
#pragma unroll
            for (int ni = 0; ni < NI; ++ni) {
                const int col = cb + ni * 16;
                float v = acc[mi][ni][r];
                if (EPI == 0) {
                    if (SCQ && col < scale_cols) v *= QSCALE;
                    ((unsigned short*)C)[(size_t)row * N + col] = f2b(v);
                } else if (EPI == 1) {
                    v += bv[ni];
                    v = 0.5f * v * (1.0f + erff(v * 0.70710678118f));
                    ((unsigned short*)C)[(size_t)row * N + col] = f2b(v);
                } else {
                    v += bv[ni] + resid[(size_t)row * N + col];
                    ((float*)C)[(size_t)row * N + col] = v;
                }
            }
        }
    }
}

// ---------------- 256^2 8-wave GEMM (4 phases/K-tile) ----------------
template <int EPI, bool SCQ>
__global__ __launch_bounds__(512, 2)
void gemm256(const unsigned short* __restrict__ A,
             const unsigned short* __restrict__ Bt,
             void* __restrict__ C,
             const float* __restrict__ bias,
             const float* __restrict__ resid,
             int M, int N, int K, int scale_cols) {
    const int nby = N / 256;
    const int nwg = gridDim.x;
    int flat = blockIdx.x;
    int wk = (flat & 7) * (nwg >> 3) + (flat >> 3);
    const int m0 = (wk / nby) * 256;
    const int n0 = (wk % nby) * 256;

    __shared__ unsigned short As[2][256 * 64];
    __shared__ unsigned short Bs[2][256 * 64];

    const int tid  = threadIdx.x;
    const int lane = tid & 63;
    const int wid  = tid >> 6;                 // 0..7
    const int wm = wid >> 2, wn = wid & 3;     // 2 x 4 waves
    const int l15 = lane & 15, q4 = lane >> 4, xw = lane & 7;

    const int sr = tid >> 3;                   // 0..63
    const int sg = (tid & 7) ^ (sr & 7);       // swizzled source granule

    const unsigned short* ag = A  + (size_t)(m0 + sr) * K + sg * 8;
    const unsigned short* bg = Bt + (size_t)(n0 + sr) * K + sg * 8;

    f32x4 acc[8][4] = {};

#define SA256(d, t, i) gload_lds16(ag + (size_t)((i) * 64) * K + (t) * 64, &As[d][(i) * 4096 + tid * 8])
#define SB256(d, t, i) gload_lds16(bg + (size_t)((i) * 64) * K + (t) * 64, &Bs[d][(i) * 4096 + tid * 8])

    const int NT = K >> 6;
#pragma unroll
    for (int i = 0; i < 4; ++i) { SA256(0, 0, i); SB256(0, 0, i); }
    wait_vmcnt<0>();
    __builtin_amdgcn_s_barrier();

    for (int t = 0; t < NT; ++t) {
        const int c = t & 1;
        const bool pf = (t + 1 < NT);
        bf16x8 breg[4];
#pragma unroll
        for (int p = 0; p < 4; ++p) {
            const int h = p >> 1, mh = p & 1;
            const int col = ((h * 4 + q4) ^ xw) << 3;
            if ((p & 1) == 0) {
#pragma unroll
                for (int ni = 0; ni < 4; ++ni)
                    breg[ni] = *(const bf16x8*)&Bs[c][(wn * 64 + ni * 16 + l15) * 64 + col];
            }
            bf16x8 a[4];
#pragma unroll
            for (int mi = 0; mi < 4; ++mi)
                a[mi] = *(const bf16x8*)&As[c][(wm * 128 + mh * 64 + mi * 16 + l15) * 64 + col];
            if (pf) {
                if (p == 0)      { SA256(c ^ 1, t + 1, 0); SB256(c ^ 1, t + 1, 0); SA256(c ^ 1, t + 1, 1); }
                else if (p == 1) { SB256(c ^ 1, t + 1, 1); SA256(c ^ 1, t + 1, 2); SB256(c ^ 1, t + 1, 2); }
                else if (p == 2) { SA256(c ^ 1, t + 1, 3); SB256(c ^ 1, t + 1, 3); }
            }
            __builtin_amdgcn_sched_barrier(0);
            asm volatile("s_waitcnt lgkmcnt(0)" ::: "memory");
            __builtin_amdgcn_sched_barrier(0);
            __builtin_amdgcn_s_setprio(1);
#pragma unroll
            for (int mi = 0; mi < 4; ++mi)
#pragma unroll
                for (int ni = 0; ni < 4; ++ni)
                    acc[mh * 4 + mi][ni] = mfma_bf16(a[mi], breg[ni], acc[mh * 4 + mi][ni]);
            __builtin_amdgcn_s_setprio(0);
            __builtin_amdgcn_sched_barrier(0);
            if (p == 3) wait_vmcnt<0>();
            __builtin_amdgcn_s_barrier();
        }
    }
#undef SA256
#undef SB256

    const int rb = m0 + wm * 128 + q4 * 4;
    const int cb = n0 + wn * 64 + l15;
    float bv[4];
    if (EPI >= 1) {
#pragma unroll
        for (int ni = 0; ni < 4; ++ni) bv[ni] = bias[cb + ni * 16];
    }
#pragma unroll
    for (int ai = 0; ai < 8; ++ai) {
#pragma unroll
        for (int r = 0; r < 4; ++r) {
            const int row = rb + ai * 16 + r;
#pragma unroll
            for (int ni = 0; ni < 4; ++ni) {
                const int col = cb + ni * 16;
                float v = acc[ai][ni][r];
                if (EPI == 0) {
                    if (SCQ && col < scale_cols) v *= QSCALE;
                    ((unsigned short*)C)[(size_t)row * N + col] = f2b(v);
                } else if (EPI == 1) {
                    v += bv[ni];
                    v = 0.5f * v * (1.0f + erff(v * 0.70710678118f));
                    ((unsigned short*)C)[(size_t)row * N + col] = f2b(v);
                } else {
                    v += bv[ni] + resid[(size_t)row * N + col];
                    ((float*)C)[(size_t)row * N + col] = v;
                }
            }
        }
    }
}

// ---------------- K/V fragment pre-pack ----------------
// pack[bh][kt (64 tiles of 32k)][slot 0..7][lane 0..63][8 elems] (8KB per tile):
//   slots 0..3 (K, QK^T A-operand):  K[b, kt*32 + (lane&31)][h*64 + sl*16 + (lane>>5)*8 + j]
//   slots 4..7 (V^T, PV A-operand):  V[b, kt*32 + c2*16 + (lane>>5)*8 + j][h*64 + dh*32 + (lane&31)]
//     with sl = 4 + dh*2 + c2
__global__ __launch_bounds__(256) void kvpack(const unsigned short* __restrict__ src,
                                              int stride, int k_off, int v_off,
                                              unsigned short* __restrict__ pack) {
    const int oct = blockIdx.x;      // 0..7 (8 k-tiles each)
    const int bh  = blockIdx.y;      // 0..31
    const int b = bh >> 4, h = bh & 15;
    const int tid = threadIdx.x;
    const int lane = tid & 63;
    const int sl = tid >> 6;         // 0..3
    const int l31 = lane & 31, l5 = lane >> 5;
    __shared__ unsigned short Kl[32 * 64], Vl[32 * 64];
    const int r = tid >> 3, c8 = (tid & 7) * 8;
    for (int t8 = 0; t8 < 8; ++t8) {
        const int kt = oct * 8 + t8;
        const int kb = kt * 32;
        *(short8*)&Kl[r * 64 + c8] = *(const short8*)&src[(size_t)(b * 2048 + kb + r) * stride + k_off + h * 64 + c8];
        *(short8*)&Vl[r * 64 + c8] = *(const short8*)&src[(size_t)(b * 2048 + kb + r) * stride + v_off + h * 64 + c8];
        __syncthreads();
        unsigned short* o = pack + (size_t)bh * 262144 + (size_t)kt * 4096;
        *(short8*)&o[sl * 512 + lane * 8] = *(const short8*)&Kl[l31 * 64 + sl * 16 + l5 * 8];
        {
            const int dh = sl >> 1, c2 = sl & 1;
            short8 vv;
#pragma unroll
            for (int j = 0; j < 8; ++j)
                vv[j] = (short)Vl[(c2 * 16 + l5 * 8 + j) * 64 + dh * 32 + l31];
            *(short8*)&o[(4 + sl) * 512 + lane * 8] = vv;
        }
        __syncthreads();
    }
}

// ---------------- flash attention v7: no-max softmax, prepacked frags ----------------
// 2 waves/block, 32 q-rows/wave, grid 1024 (XCD-clustered bh). Staging = linear 16KB
// memcpy of 2 packed 32k-tiles per iteration (global_load_lds, coalesced); fragment
// reads are ds_read_b128 at base + IMMEDIATE offsets (no addr VALU, no conflicts).
// Softmax without online max: s bounded (|s| <= scale*|q||k| ~ 26) => exp2(s) safe in
// f32/bf16; l accumulated per-lane in f32x16, single tree at end. T12 cvt_pk+permlane.
__global__ __launch_bounds__(128) void attn(const unsigned short* __restrict__ Q, int q_stride, int q_off,
                                            const unsigned short* __restrict__ pack,
                                            const float* __restrict__ res,
                                            float* __restrict__ out) {
    const int bid = blockIdx.x;            // 0..1023
    const int slot = bid >> 3;             // 0..127
    const int bh = (bid & 7) * 4 + (slot >> 5);
    const int qt = slot & 31;
    const int b = bh >> 4, h = bh & 15;
    const int lane = threadIdx.x & 63, w = threadIdx.x >> 6;  // w in {0,1}
    const int l31 = lane & 31, l5 = lane >> 5;

    __shared__ unsigned short lds[2][8192];   // 16KB per buffer = one 64k iteration

    const int q0 = qt * 64 + w * 32;

    // Q fragments (B-operand): col q = l31, d = i*16 + l5*8 + j
    const unsigned short* qp = Q + (size_t)(b * 2048 + q0 + l31) * q_stride + q_off + h * 64 + l5 * 8;
    bf16x8 qf[4];
#pragma unroll
    for (int i = 0; i < 4; ++i) qf[i] = *(const bf16x8*)&qp[i * 16];

    const unsigned short* pkb = pack + (size_t)bh * 262144;

    f32x16 oacc[2] = {};
    f32x16 lacc = {};

    // stage 2 packed 32k-tiles (16KB): 16 chunks of 1KB, 8 per wave, all contiguous
    auto STAGE = [&](int d, int t) {
        const unsigned short* s = pkb + (size_t)t * 8192;
#pragma unroll
        for (int i = 0; i < 8; ++i) {
            const int ch = i * 2 + w;
            gload_lds16(s + ch * 512 + lane * 8, &lds[d][ch * 512 + lane * 8]);
        }
    };

    STAGE(0, 0);

    for (int t = 0; t < 32; ++t) {
        const int cur = t & 1;
        if (t + 1 < 32) STAGE(cur ^ 1, t + 1);
        __builtin_amdgcn_sched_barrier(0);
        if (t + 1 < 32) wait_vmcnt<8>();   // this tile's 8 loads done; next tile's in flight
        else            wait_vmcnt<0>();
        __builtin_amdgcn_s_barrier();
        __builtin_amdgcn_sched_barrier(0);

        const unsigned short* L = &lds[cur][lane * 8];

        // K fragments: slot ks*?|i at imm offsets
        bf16x8 kf[2][4];
#pragma unroll
        for (int ks = 0; ks < 2; ++ks)
#pragma unroll
            for (int i = 0; i < 4; ++i)
                kf[ks][i] = *(const bf16x8*)&L[ks * 4096 + i * 512];

        f32x16 s0 = {}, s1 = {};
        __builtin_amdgcn_s_setprio(1);
#pragma unroll
        for (int i = 0; i < 4; ++i) s0 = mfma32(kf[0][i], qf[i], s0);
#pragma unroll
        for (int i = 0; i < 4; ++i) s1 = mfma32(kf[1][i], qf[i], s1);
        __builtin_amdgcn_s_setprio(0);

        // V fragments: vf[dh][jj], jj = ks*2 + c2
        bf16x8 vf[2][4];
#pragma unroll
        for (int dh = 0; dh < 2; ++dh)
#pragma unroll
            for (int jj = 0; jj < 4; ++jj)
                vf[dh][jj] = *(const bf16x8*)&L[(jj >> 1) * 4096 + (4 + dh * 2 + (jj & 1)) * 512];

        // softmax without max-subtraction: p = 2^s directly (s bounded)
        float p0[16], p1[16];
#pragma unroll
        for (int r = 0; r < 16; ++r) p0[r] = __builtin_amdgcn_exp2f(s0[r]);
#pragma unroll
        for (int r = 0; r < 16; ++r) p1[r] = __builtin_amdgcn_exp2f(s1[r]);
#pragma unroll
        for (int r = 0; r < 16; ++r) lacc[r] += p0[r] + p1[r];

        // P^T -> B-operand fragments via cvt_pk + permlane32_swap (T12)
        bf16x8 pf[4];
#pragma unroll
        for (int half = 0; half < 2; ++half) {
            const float* p = half ? p1 : p0;
#pragma unroll
            for (int c = 0; c < 2; ++c) {
                unsigned a0 = cvt_pk_bf16(p[8 * c + 0], p[8 * c + 1]);
                unsigned a1 = cvt_pk_bf16(p[8 * c + 4], p[8 * c + 5]);
                unsigned b0 = cvt_pk_bf16(p[8 * c + 2], p[8 * c + 3]);
                unsigned b1 = cvt_pk_bf16(p[8 * c + 6], p[8 * c + 7]);
                asm volatile("v_permlane32_swap_b32 %0, %1" : "+v"(a0), "+v"(a1));
                asm volatile("v_permlane32_swap_b32 %0, %1" : "+v"(b0), "+v"(b1));
                union { unsigned u[4]; bf16x8 v; } pu;
                pu.u[0] = a0; pu.u[1] = b0; pu.u[2] = a1; pu.u[3] = b1;
                pf[half * 2 + c] = pu.v;
            }
        }

        // O^T += V^T · P^T
        __builtin_amdgcn_s_setprio(1);
#pragma unroll
        for (int dh = 0; dh < 2; ++dh)
#pragma unroll
            for (int jj = 0; jj < 4; ++jj)
                oacc[dh] = mfma32(vf[dh][jj], pf[jj], oacc[dh]);
        __builtin_amdgcn_s_setprio(0);

        __builtin_amdgcn_s_barrier();   // buf cur fully read before next re-stage
    }

    // final l: tree over 16 regs + cross-half shuffle
    float lsum[16];
#pragma unroll
    for (int r = 0; r < 16; ++r) lsum[r] = lacc[r];
#pragma unroll
    for (int off = 8; off >= 1; off >>= 1)
#pragma unroll
        for (int r = 0; r < off; ++r) lsum[r] += lsum[r + off];
    const float l = lsum[0] + __shfl_xor(lsum[0], 32);

    // epilogue: O/l + residual.  d_local = (reg&3) + 8*(reg>>2) + 4*l5
    const float inv = 1.0f / l;
    const size_t rowoff = (size_t)(b * 2048 + q0 + l31) * 1024 + h * 64;
#pragma unroll
    for (int dh = 0; dh < 2; ++dh) {
#pragma unroll
        for (int g = 0; g < 4; ++g) {
            const int col = dh * 32 + g * 8 + l5 * 4;
            f32x4 rv = *(const f32x4*)&res[rowoff + col];
            f32x4 ov;
#pragma unroll
            for (int r = 0; r < 4; ++r) ov[r] = oacc[dh][g * 4 + r] * inv + rv[r];
            *(f32x4*)&out[rowoff + col] = ov;
        }
    }
}

// ---------------- host ----------------
extern "C" void kernel_launch(void* const* d_in, const int* in_sizes, int n_in,
                              void* d_out, int out_size, void* d_ws, size_t ws_size,
                              hipStream_t stream) {
    const float* x      = (const float*)d_in[0];
    const float* feat   = (const float*)d_in[1];
    const float* norm_g = (const float*)d_in[2];
    const float* norm_b = (const float*)d_in[3];
    const float* W_cq   = (const float*)d_in[4];
    const float* W_ckv  = (const float*)d_in[5];
    const float* W_sqkv = (const float*)d_in[6];
    const float* ffn_g  = (const float*)d_in[7];
    const float* ffn_b  = (const float*)d_in[8];
    const float* W1     = (const float*)d_in[9];
    const float* b1     = (const float*)d_in[10];
    const float* W2     = (const float*)d_in[11];
    const float* b2     = (const float*)d_in[12];
    float* out = (float*)d_out;

    char* ws = (char*)d_ws;
    unsigned short* wq_t   = (unsigned short*)(ws + (size_t)(0u)   * (1u << 20));  // 2MB
    unsigned short* wkv_t  = (unsigned short*)(ws + (size_t)(2u)   * (1u << 20));  // 1.5MB
    unsigned short* wqkv_t = (unsigned short*)(ws + (size_t)(4u)   * (1u << 20));  // 6MB
    unsigned short* w1_t   = (unsigned short*)(ws + (size_t)(10u)  * (1u << 20));  // 8MB
    unsigned short* w2_t   = (unsigned short*)(ws + (size_t)(18u)  * (1u << 20));  // 8MB
    unsigned short* featb  = (unsigned short*)(ws + (size_t)(26u)  * (1u << 20));  // 3MB
    unsigned short* t0     = (unsigned short*)(ws + (size_t)(29u)  * (1u << 20));  // 8MB
    float*          cross  = (float*)        (ws + (size_t)(37u)  * (1u << 20));   // 16MB
    unsigned short* qb     = (unsigned short*)(ws + (size_t)(53u)  * (1u << 20));  // 8MB
    unsigned short* kvb    = (unsigned short*)(ws + (size_t)(61u)  * (1u << 20));  // 16MB
    unsigned short* qkvb   = (unsigned short*)(ws + (size_t)(77u)  * (1u << 20));  // 24MB
    unsigned short* packb  = (unsigned short*)(ws + (size_t)(101u) * (1u << 20));  // 16MB
    unsigned short* h1     = (unsigned short*)(ws + (size_t)(53u)  * (1u << 20));  // 32MB (aliases q/kv/qkv, dead by FFN)

    // weights -> bf16 transposed [N,K]
    wconv_t<<<dim3(1024 / 32, 1024 / 32), 256, 0, stream>>>(W_cq,   wq_t,   1024, 1024);
    wconv_t<<<dim3(384 / 32,  2048 / 32), 256, 0, stream>>>(W_ckv,  wkv_t,  384,  2048);
    wconv_t<<<dim3(1024 / 32, 3072 / 32), 256, 0, stream>>>(W_sqkv, wqkv_t, 1024, 3072);
    wconv_t<<<dim3(1024 / 32, 4096 / 32), 256, 0, stream>>>(W1,     w1_t,   1024, 4096);
    wconv_t<<<dim3(4096 / 32, 1024 / 32), 256, 0, stream>>>(W2,     w2_t,   4096, 1024);
    fconv<<<dim3((4096 * 384 / 4) / 256), 256, 0, stream>>>(feat, featb, 4096 * 384 / 4);

    // ---- cross attention ----
    lnorm<<<4096, 256, 0, stream>>>(x, norm_g, norm_b, t0);
    gemm8<2, 2, 4, 2, 0, true ><<<512, 256, 0, stream>>>(t0,    wq_t,  qb,  nullptr, nullptr, 4096, 1024, 1024, 1024);
    gemm8<2, 2, 4, 4, 0, false><<<512, 256, 0, stream>>>(featb, wkv_t, kvb, nullptr, nullptr, 4096, 2048, 384,  0);
    kvpack<<<dim3(8, 32), 256, 0, stream>>>(kvb, 2048, 0, 1024, packb);
    attn<<<1024, 128, 0, stream>>>(qb, 1024, 0, packb, x, cross);

    // ---- self attention ----
    lnorm<<<4096, 256, 0, stream>>>(cross, norm_g, norm_b, t0);
    gemm256<0, true ><<<192, 512, 0, stream>>>(t0, wqkv_t, qkvb, nullptr, nullptr, 4096, 3072, 1024, 1024);
    kvpack<<<dim3(8, 32), 256, 0, stream>>>(qkvb, 3072, 1024, 2048, packb);
    attn<<<1024, 128, 0, stream>>>(qkvb, 3072, 0, packb, cross, out);

    // ---- FFN ----
    lnorm<<<4096, 256, 0, stream>>>(out, ffn_g, ffn_b, t0);
    gemm256<1, false><<<256, 512, 0, stream>>>(t0, w1_t, h1, b1, nullptr, 4096, 4096, 1024, 0);
    gemm8<2, 2, 4, 2, 2, false><<<512, 256, 0, stream>>>(h1, w2_t, out, b2, (const float*)out, 4096, 1024, 4096, 0);
}

// Round 10
// 329.484 us; speedup vs baseline: 1.1680x; 1.0084x over previous
//
#include <hip/hip_runtime.h>
#include <math.h>
#include <stdint.h>

typedef __attribute__((ext_vector_type(8)))  short   short8;
typedef __attribute__((ext_vector_type(4)))  short   short4v;
typedef __attribute__((ext_vector_type(8)))  __bf16  bf16x8;
typedef __attribute__((ext_vector_type(4)))  float   f32x4;
typedef __attribute__((ext_vector_type(16))) float   f32x16;

__device__ __forceinline__ unsigned short f2b(float f) {
    union { float f; unsigned u; } v; v.f = f;
    unsigned r = v.u + 0x7FFF + ((v.u >> 16) & 1);
    return (unsigned short)(r >> 16);
}

__device__ __forceinline__ f32x4 mfma_bf16(bf16x8 a, bf16x8 b, f32x4 c) {
    return __builtin_amdgcn_mfma_f32_16x16x32_bf16(a, b, c, 0, 0, 0);
}

__device__ __forceinline__ f32x16 mfma32(bf16x8 a, bf16x8 b, f32x16 c) {
    return __builtin_amdgcn_mfma_f32_32x32x16_bf16(a, b, c, 0, 0, 0);
}

__device__ __forceinline__ unsigned cvt_pk_bf16(float lo, float hi) {
    unsigned r;
    asm volatile("v_cvt_pk_bf16_f32 %0, %1, %2" : "=v"(r) : "v"(lo), "v"(hi));
    return r;
}

__device__ __forceinline__ void gload_lds16(const unsigned short* g, unsigned short* l) {
    __builtin_amdgcn_global_load_lds(
        (const __attribute__((address_space(1))) void*)g,
        (__attribute__((address_space(3))) void*)l,
        16, 0, 0);
}

template <int N>
__device__ __forceinline__ void wait_vmcnt() {
    if constexpr (N == 0)       asm volatile("s_waitcnt vmcnt(0)" ::: "memory");
    else if constexpr (N == 4)  asm volatile("s_waitcnt vmcnt(4)" ::: "memory");
    else if constexpr (N == 6)  asm volatile("s_waitcnt vmcnt(6)" ::: "memory");
    else if constexpr (N == 8)  asm volatile("s_waitcnt vmcnt(8)" ::: "memory");
    else                        static_assert(N == 0 || N == 4 || N == 6 || N == 8, "add vmcnt case");
}

// 0.125 (d_head^-0.5) * log2(e): softmax computed in base-2 (exact rescale)
#define QSCALE 0.18033688011112042592f

// ---------------- weight transpose + f32->bf16 ----------------
__global__ __launch_bounds__(256) void wconv_t(const float* __restrict__ W,
                                               unsigned short* __restrict__ Wt,
                                               int K, int N) {
    __shared__ float tile[32][33];
    int bk = blockIdx.x * 32;
    int bn = blockIdx.y * 32;
    int tx = threadIdx.x & 31, ty = threadIdx.x >> 5;  // 32 x 8
#pragma unroll
    for (int i = 0; i < 4; ++i) {
        int r = ty + i * 8;
        tile[r][tx] = W[(size_t)(bk + r) * N + bn + tx];
    }
    __syncthreads();
#pragma unroll
    for (int i = 0; i < 4; ++i) {
        int r = ty + i * 8;
        Wt[(size_t)(bn + r) * K + bk + tx] = f2b(tile[tx][r]);
    }
}

// ---------------- f32 -> bf16 elementwise (x4) ----------------
__global__ __launch_bounds__(256) void fconv(const float* __restrict__ in,
                                             unsigned short* __restrict__ out, int n4) {
    int i = blockIdx.x * 256 + threadIdx.x;
    if (i >= n4) return;
    f32x4 v = ((const f32x4*)in)[i];
    short4v o;
    o.x = (short)f2b(v.x); o.y = (short)f2b(v.y);
    o.z = (short)f2b(v.z); o.w = (short)f2b(v.w);
    ((short4v*)out)[i] = o;
}

// ---------------- layernorm (C=1024), f32 in -> bf16 out ----------------
__global__ __launch_bounds__(256) void lnorm(const float* __restrict__ x,
                                             const float* __restrict__ g,
                                             const float* __restrict__ bta,
                                             unsigned short* __restrict__ out) {
    int row = blockIdx.x;
    const f32x4* xr = (const f32x4*)(x + (size_t)row * 1024);
    int t = threadIdx.x;
    f32x4 v = xr[t];
    float s  = v.x + v.y + v.z + v.w;
    float s2 = v.x * v.x + v.y * v.y + v.z * v.z + v.w * v.w;
#pragma unroll
    for (int m = 1; m < 64; m <<= 1) {
        s  += __shfl_xor(s, m);
        s2 += __shfl_xor(s2, m);
    }
    __shared__ float rs[8];
    int w = t >> 6;
    if ((t & 63) == 0) { rs[w] = s; rs[4 + w] = s2; }
    __syncthreads();
    s  = rs[0] + rs[1] + rs[2] + rs[3];
    s2 = rs[4] + rs[5] + rs[6] + rs[7];
    float mean = s * (1.0f / 1024.0f);
    float var  = s2 * (1.0f / 1024.0f) - mean * mean;
    float rstd = rsqrtf(var + 1e-5f);
    f32x4 gv = ((const f32x4*)g)[t];
    f32x4 bv = ((const f32x4*)bta)[t];
    short4v o;
    o.x = (short)f2b((v.x - mean) * rstd * gv.x + bv.x);
    o.y = (short)f2b((v.y - mean) * rstd * gv.y + bv.y);
    o.z = (short)f2b((v.z - mean) * rstd * gv.z + bv.z);
    o.w = (short)f2b((v.w - mean) * rstd * gv.w + bv.w);
    ((short4v*)(out + (size_t)row * 1024))[t] = o;
}

// ---------------- pipelined GEMM: A[M,K] x Bt[N,K] -> C[M,N], BK=64 ----------------
template <int WM, int WN, int MI, int NI, int EPI, bool SCQ>
__global__ __launch_bounds__(WM * WN * 64, 2)
void gemm8(const unsigned short* __restrict__ A,
           const unsigned short* __restrict__ Bt,
           void* __restrict__ C,
           const float* __restrict__ bias,
           const float* __restrict__ resid,
           int M, int N, int K, int scale_cols) {
    constexpr int BM = WM * MI * 16;
    constexpr int BN = WN * NI * 16;
    constexpr int THREADS = WM * WN * 64;
    constexpr int ROWS = THREADS / 8;          // rows per stage instr
    constexpr int IA = BM / ROWS;              // stage instrs for A
    constexpr int IB = BN / ROWS;

    // bijective XCD swizzle (all grids are multiples of 8), m-major per XCD
    const int nwg = gridDim.x;
    const int nby = N / BN;
    int flat = blockIdx.x;
    int wk = (flat & 7) * (nwg >> 3) + (flat >> 3);
    const int m0 = (wk / nby) * BM;
    const int n0 = (wk % nby) * BN;

    __shared__ unsigned short As[2][BM * 64];
    __shared__ unsigned short Bs[2][BN * 64];

    const int tid  = threadIdx.x;
    const int lane = tid & 63;
    const int wid  = tid >> 6;
    const int wm = wid / WN, wn = wid % WN;
    const int l15 = lane & 15, q4 = lane >> 4, xw = lane & 7;

    const int sr = tid >> 3;                    // stage row within group
    const int sg = (tid & 7) ^ (sr & 7);        // swizzled source granule

    const unsigned short* ag = A  + (size_t)(m0 + sr) * K + sg * 8;
    const unsigned short* bg = Bt + (size_t)(n0 + sr) * K + sg * 8;

    f32x4 acc[MI][NI] = {};

    auto STAGE = [&](int d, int t) {
        const int k0 = t * 64;
#pragma unroll
        for (int i = 0; i < IA; ++i)
            gload_lds16(ag + (size_t)(i * ROWS) * K + k0, &As[d][i * ROWS * 64 + tid * 8]);
#pragma unroll
        for (int i = 0; i < IB; ++i)
            gload_lds16(bg + (size_t)(i * ROWS) * K + k0, &Bs[d][i * ROWS * 64 + tid * 8]);
    };

    const int NT = K >> 6;
    STAGE(0, 0);

    for (int t = 0; t < NT; ++t) {
        const int c = t & 1;
        if (t + 1 < NT) STAGE(c ^ 1, t + 1);
        __builtin_amdgcn_sched_barrier(0);
        if (t + 1 < NT) wait_vmcnt<IA + IB>();
        else            wait_vmcnt<0>();
        __builtin_amdgcn_s_barrier();
        __builtin_amdgcn_sched_barrier(0);
#pragma unroll
        for (int h = 0; h < 2; ++h) {
            bf16x8 a[MI], b[NI];
            const int gsl = h * 4 + q4;         // granule before swizzle
#pragma unroll
            for (int mi = 0; mi < MI; ++mi)
                a[mi] = *(const bf16x8*)&As[c][(wm * MI * 16 + mi * 16 + l15) * 64 + ((gsl ^ xw) << 3)];
#pragma unroll
            for (int ni = 0; ni < NI; ++ni)
                b[ni] = *(const bf16x8*)&Bs[c][(wn * NI * 16 + ni * 16 + l15) * 64 + ((gsl ^ xw) << 3)];
            __builtin_amdgcn_s_setprio(1);
#pragma unroll
            for (int mi = 0; mi < MI; ++mi)
#pragma unroll
                for (int ni = 0; ni < NI; ++ni)
                    acc[mi][ni] = mfma_bf16(a[mi], b[ni], acc[mi][ni]);
            __builtin_amdgcn_s_setprio(0);
        }
        __builtin_amdgcn_sched_barrier(0);
        __builtin_amdgcn_s_barrier();
    }

    // epilogue
    const int rb = m0 + wm * MI * 16 + q4 * 4;
    const int cb = n0 + wn * NI * 16 + l15;
    float bv[NI];
    if (EPI >= 1) {
#pragma unroll
        for (int ni = 0; ni < NI; ++ni) bv[ni] = bias[cb + ni * 16];
    }
#pragma unroll
    for (int mi = 0; mi < MI; ++mi) {
#pragma unroll
        for (int r = 0; r < 4; ++r) {
            const int row = rb + mi * 16 + r;
#pragma unroll
            for (int ni = 0; ni < NI; ++ni) {
                const int col = cb + ni * 16;
                float v = acc[mi][ni][r];
                if (EPI == 0) {
                    if (SCQ && col < scale_cols) v *= QSCALE;
                    ((unsigned short*)C)[(size_t)row * N + col] = f2b(v);
                } else if (EPI == 1) {
                    v += bv[ni];
                    v = 0.5f * v * (1.0f + erff(v * 0.70710678118f));
                    ((unsigned short*)C)[(size_t)row * N + col] = f2b(v);
                } else {
                    v += bv[ni] + resid[(size_t)row * N + col];
                    ((float*)C)[(size_t)row * N + col] = v;
                }
            }
        }
    }
}

// ---------------- 256^2 8-wave GEMM (4 phases/K-tile) ----------------
template <int EPI, bool SCQ>
__global__ __launch_bounds__(512, 2)
void gemm256(const unsigned short* __restrict__ A,
             const unsigned short* __restrict__ Bt,
             void* __restrict__ C,
             const float* __restrict__ bias,
             const float* __restrict__ resid,
             int M, int N, int K, int scale_cols) {
    const int nby = N / 256;
    const int nwg = gridDim.x;
    int flat = blockIdx.x;
    int wk = (flat & 7) * (nwg >> 3) + (flat >> 3);
    const int m0 = (wk / nby) * 256;
    const int n0 = (wk % nby) * 256;

    __shared__ unsigned short As[2][256 * 64];
    __shared__ unsigned short Bs[2][256 * 64];

    const int tid  = threadIdx.x;
    const int lane = tid & 63;
    const int wid  = tid >> 6;                 // 0..7
    const int wm = wid >> 2, wn = wid & 3;     // 2 x 4 waves
    const int l15 = lane & 15, q4 = lane >> 4, xw = lane & 7;

    const int sr = tid >> 3;                   // 0..63
    const int sg = (tid & 7) ^ (sr & 7);       // swizzled source granule

    const unsigned short* ag = A  + (size_t)(m0 + sr) * K + sg * 8;
    const unsigned short* bg = Bt + (size_t)(n0 + sr) * K + sg * 8;

    f32x4 acc[8][4] = {};

#define SA256(d, t, i) gload_lds16(ag + (size_t)((i) * 64) * K + (t) * 64, &As[d][(i) * 4096 + tid * 8])
#define SB256(d, t, i) gload_lds16(bg + (size_t)((i) * 64) * K + (t) * 64, &Bs[d][(i) * 4096 + tid * 8])

    const int NT = K >> 6;
#pragma unroll
    for (int i = 0; i < 4; ++i) { SA256(0, 0, i); SB256(0, 0, i); }
    wait_vmcnt<0>();
    __builtin_amdgcn_s_barrier();

    for (int t = 0; t < NT; ++t) {
        const int c = t & 1;
        const bool pf = (t + 1 < NT);
        bf16x8 breg[4];
#pragma unroll
        for (int p = 0; p < 4; ++p) {
            const int h = p >> 1, mh = p & 1;
            const int col = ((h * 4 + q4) ^ xw) << 3;
            if ((p & 1) == 0) {
#pragma unroll
                for (int ni = 0; ni < 4; ++ni)
                    breg[ni] = *(const bf16x8*)&Bs[c][(wn * 64 + ni * 16 + l15) * 64 + col];
            }
            bf16x8 a[4];
#pragma unroll
            for (int mi = 0; mi < 4; ++mi)
                a[mi] = *(const bf16x8*)&As[c][(wm * 128 + mh * 64 + mi * 16 + l15) * 64 + col];
            if (pf) {
                if (p == 0)      { SA256(c ^ 1, t + 1, 0); SB256(c ^ 1, t + 1, 0); SA256(c ^ 1, t + 1, 1); }
                else if (p == 1) { SB256(c ^ 1, t + 1, 1); SA256(c ^ 1, t + 1, 2); SB256(c ^ 1, t + 1, 2); }
                else if (p == 2) { SA256(c ^ 1, t + 1, 3); SB256(c ^ 1, t + 1, 3); }
            }
            __builtin_amdgcn_sched_barrier(0);
            asm volatile("s_waitcnt lgkmcnt(0)" ::: "memory");
            __builtin_amdgcn_sched_barrier(0);
            __builtin_amdgcn_s_setprio(1);
#pragma unroll
            for (int mi = 0; mi < 4; ++mi)
#pragma unroll
                for (int ni = 0; ni < 4; ++ni)
                    acc[mh * 4 + mi][ni] = mfma_bf16(a[mi], breg[ni], acc[mh * 4 + mi][ni]);
            __builtin_amdgcn_s_setprio(0);
            __builtin_amdgcn_sched_barrier(0);
            if (p == 3) wait_vmcnt<0>();
            __builtin_amdgcn_s_barrier();
        }
    }
#undef SA256
#undef SB256

    const int rb = m0 + wm * 128 + q4 * 4;
    const int cb = n0 + wn * 64 + l15;
    float bv[4];
    if (EPI >= 1) {
#pragma unroll
        for (int ni = 0; ni < 4; ++ni) bv[ni] = bias[cb + ni * 16];
    }
#pragma unroll
    for (int ai = 0; ai < 8; ++ai) {
#pragma unroll
        for (int r = 0; r < 4; ++r) {
            const int row = rb + ai * 16 + r;
#pragma unroll
            for (int ni = 0; ni < 4; ++ni) {
                const int col = cb + ni * 16;
                float v = acc[ai][ni][r];
                if (EPI == 0) {
                    if (SCQ && col < scale_cols) v *= QSCALE;
                    ((unsigned short*)C)[(size_t)row * N + col] = f2b(v);
                } else if (EPI == 1) {
                    v += bv[ni];
                    v = 0.5f * v * (1.0f + erff(v * 0.70710678118f));
                    ((unsigned short*)C)[(size_t)row * N + col] = f2b(v);
                } else {
                    v += bv[ni] + resid[(size_t)row * N + col];
                    ((float*)C)[(size_t)row * N + col] = v;
                }
            }
        }
    }
}

// ---------------- K/V fragment pre-pack ----------------
// pack[bh][kt (64 tiles of 32k)][slot 0..7][lane 0..63][8 elems] (8KB per tile):
//   slots 0..3 (K, QK^T A-operand):  K[b, kt*32 + (lane&31)][h*64 + sl*16 + (lane>>5)*8 + j]
//   slots 4..7 (V^T, PV A-operand):  V[b, kt*32 + c2*16 + (lane>>5)*8 + j][h*64 + dh*32 + (lane&31)]
//     with sl = 4 + dh*2 + c2
__global__ __launch_bounds__(256) void kvpack(const unsigned short* __restrict__ src,
                                              int stride, int k_off, int v_off,
                                              unsigned short* __restrict__ pack) {
    const int oct = blockIdx.x;      // 0..7 (8 k-tiles each)
    const int bh  = blockIdx.y;      // 0..31
    const int b = bh >> 4, h = bh & 15;
    const int tid = threadIdx.x;
    const int lane = tid & 63;
    const int sl = tid >> 6;         // 0..3
    const int l31 = lane & 31, l5 = lane >> 5;
    __shared__ unsigned short Kl[32 * 64], Vl[32 * 64];
    const int r = tid >> 3, c8 = (tid & 7) * 8;
    for (int t8 = 0; t8 < 8; ++t8) {
        const int kt = oct * 8 + t8;
        const int kb = kt * 32;
        *(short8*)&Kl[r * 64 + c8] = *(const short8*)&src[(size_t)(b * 2048 + kb + r) * stride + k_off + h * 64 + c8];
        *(short8*)&Vl[r * 64 + c8] = *(const short8*)&src[(size_t)(b * 2048 + kb + r) * stride + v_off + h * 64 + c8];
        __syncthreads();
        unsigned short* o = pack + (size_t)bh * 262144 + (size_t)kt * 4096;
        *(short8*)&o[sl * 512 + lane * 8] = *(const short8*)&Kl[l31 * 64 + sl * 16 + l5 * 8];
        {
            const int dh = sl >> 1, c2 = sl & 1;
            short8 vv;
#pragma unroll
            for (int j = 0; j < 8; ++j)
                vv[j] = (short)Vl[(c2 * 16 + l5 * 8 + j) * 64 + dh * 32 + l31];
            *(short8*)&o[(4 + sl) * 512 + lane * 8] = vv;
        }
        __syncthreads();
    }
}

// ---------------- flash attention v8: no-max softmax, k-split, 4 waves/block ----------------
// Block = 256 threads: wave (qg = w>>1, ks = w&1). Each iteration stages one packed
// 64k double-tile (16KB, 4 chunks/wave); wave ks consumes packed sub-tile ks (32 k):
// 4 QK MFMA -> 16 exp2 -> pack -> 4 PV MFMA. No online max (S bounded: exp2 safe in
// f32); O and l are plain sums over k, so the two k-split waves merge by ADDITION at
// the end through (reused) staging LDS. 1024 blocks -> 4 blocks/CU = 4 waves/SIMD.
__global__ __launch_bounds__(256) void attn(const unsigned short* __restrict__ Q, int q_stride, int q_off,
                                            const unsigned short* __restrict__ pack,
                                            const float* __restrict__ res,
                                            float* __restrict__ out) {
    const int bid = blockIdx.x;            // 0..1023
    const int slot = bid >> 3;             // 0..127
    const int bh = (bid & 7) * 4 + (slot >> 5);
    const int qt = slot & 31;              // 64 q-rows per block
    const int b = bh >> 4, h = bh & 15;
    const int tid = threadIdx.x;
    const int lane = tid & 63, w = tid >> 6;   // w in 0..3
    const int qg = w >> 1, ks = w & 1;
    const int l31 = lane & 31, l5 = lane >> 5;

    __shared__ unsigned short lds[2][8192];    // 16KB per buffer; reused for merge

    const int q0 = qt * 64 + qg * 32;

    // Q fragments (B-operand): col q = l31, d = i*16 + l5*8 + j
    const unsigned short* qp = Q + (size_t)(b * 2048 + q0 + l31) * q_stride + q_off + h * 64 + l5 * 8;
    bf16x8 qf[4];
#pragma unroll
    for (int i = 0; i < 4; ++i) qf[i] = *(const bf16x8*)&qp[i * 16];

    const unsigned short* pkb = pack + (size_t)bh * 262144;

    f32x16 oacc[2] = {};
    f32x16 lacc = {};

    // stage one packed 64k double-tile (16 chunks of 1KB; 4 per wave)
    auto STAGE = [&](int d, int t) {
        const unsigned short* s = pkb + (size_t)t * 8192;
#pragma unroll
        for (int i = 0; i < 4; ++i) {
            const int ch = i * 4 + w;
            gload_lds16(s + ch * 512 + lane * 8, &lds[d][ch * 512 + lane * 8]);
        }
    };

    STAGE(0, 0);

    for (int t = 0; t < 32; ++t) {
        const int cur = t & 1;
        if (t + 1 < 32) STAGE(cur ^ 1, t + 1);
        __builtin_amdgcn_sched_barrier(0);
        if (t + 1 < 32) wait_vmcnt<4>();   // own tile-t loads done; t+1's in flight
        else            wait_vmcnt<0>();
        __builtin_amdgcn_s_barrier();      // wait-THEN-barrier => cross-wave staging safe
        __builtin_amdgcn_sched_barrier(0);

        // this wave's 32k sub-tile
        const unsigned short* L = &lds[cur][ks * 4096 + lane * 8];

        bf16x8 kf[4];
#pragma unroll
        for (int i = 0; i < 4; ++i) kf[i] = *(const bf16x8*)&L[i * 512];

        f32x16 s = {};
        __builtin_amdgcn_s_setprio(1);
#pragma unroll
        for (int i = 0; i < 4; ++i) s = mfma32(kf[i], qf[i], s);
        __builtin_amdgcn_s_setprio(0);

        bf16x8 vf[2][2];
#pragma unroll
        for (int dh = 0; dh < 2; ++dh)
#pragma unroll
            for (int c2 = 0; c2 < 2; ++c2)
                vf[dh][c2] = *(const bf16x8*)&L[(4 + dh * 2 + c2) * 512];

        // softmax without max-subtraction: p = 2^s (s bounded)
        float p[16];
#pragma unroll
        for (int r = 0; r < 16; ++r) p[r] = __builtin_amdgcn_exp2f(s[r]);
#pragma unroll
        for (int r = 0; r < 16; ++r) lacc[r] += p[r];

        // P^T -> B-operand fragments (T12 cvt_pk + permlane32_swap)
        bf16x8 pf[2];
#pragma unroll
        for (int c = 0; c < 2; ++c) {
            unsigned a0 = cvt_pk_bf16(p[8 * c + 0], p[8 * c + 1]);
            unsigned a1 = cvt_pk_bf16(p[8 * c + 4], p[8 * c + 5]);
            unsigned b0 = cvt_pk_bf16(p[8 * c + 2], p[8 * c + 3]);
            unsigned b1 = cvt_pk_bf16(p[8 * c + 6], p[8 * c + 7]);
            asm volatile("v_permlane32_swap_b32 %0, %1" : "+v"(a0), "+v"(a1));
            asm volatile("v_permlane32_swap_b32 %0, %1" : "+v"(b0), "+v"(b1));
            union { unsigned u[4]; bf16x8 v; } pu;
            pu.u[0] = a0; pu.u[1] = b0; pu.u[2] = a1; pu.u[3] = b1;
            pf[c] = pu.v;
        }

        // O^T += V^T · P^T (this wave's 32k)
        __builtin_amdgcn_s_setprio(1);
#pragma unroll
        for (int dh = 0; dh < 2; ++dh)
#pragma unroll
            for (int c2 = 0; c2 < 2; ++c2)
                oacc[dh] = mfma32(vf[dh][c2], pf[c2], oacc[dh]);
        __builtin_amdgcn_s_setprio(0);

        __builtin_amdgcn_s_barrier();   // buf cur fully read before re-stage
    }

    // in-wave l reduce: tree over 16 regs + cross-half shuffle
    float lsum[16];
#pragma unroll
    for (int r = 0; r < 16; ++r) lsum[r] = lacc[r];
#pragma unroll
    for (int off = 8; off >= 1; off >>= 1)
#pragma unroll
        for (int r = 0; r < off; ++r) lsum[r] += lsum[r + off];
    float lh = lsum[0] + __shfl_xor(lsum[0], 32);   // this wave's half-l

    // k-split merge through reused staging LDS (padded stride 33: conflict-free)
    float* mb = (float*)&lds[qg][0];   // 2112 floats needed, 4096 available
    if (ks == 1) {
#pragma unroll
        for (int dh = 0; dh < 2; ++dh)
#pragma unroll
            for (int r = 0; r < 16; ++r)
                mb[lane * 33 + dh * 16 + r] = oacc[dh][r];
        mb[lane * 33 + 32] = lh;
    }
    __syncthreads();
    if (ks == 0) {
#pragma unroll
        for (int dh = 0; dh < 2; ++dh)
#pragma unroll
            for (int r = 0; r < 16; ++r)
                oacc[dh][r] += mb[lane * 33 + dh * 16 + r];
        const float l = lh + mb[lane * 33 + 32];

        // epilogue: O/l + residual.  d_local = (reg&3) + 8*(reg>>2) + 4*l5
        const float inv = 1.0f / l;
        const size_t rowoff = (size_t)(b * 2048 + q0 + l31) * 1024 + h * 64;
#pragma unroll
        for (int dh = 0; dh < 2; ++dh) {
#pragma unroll
            for (int g = 0; g < 4; ++g) {
                const int col = dh * 32 + g * 8 + l5 * 4;
                f32x4 rv = *(const f32x4*)&res[rowoff + col];
                f32x4 ov;
#pragma unroll
                for (int r = 0; r < 4; ++r) ov[r] = oacc[dh][g * 4 + r] * inv + rv[r];
                *(f32x4*)&out[rowoff + col] = ov;
            }
        }
    }
}

// ---------------- host ----------------
extern "C" void kernel_launch(void* const* d_in, const int* in_sizes, int n_in,
                              void* d_out, int out_size, void* d_ws, size_t ws_size,
                              hipStream_t stream) {
    const float* x      = (const float*)d_in[0];
    const float* feat   = (const float*)d_in[1];
    const float* norm_g = (const float*)d_in[2];
    const float* norm_b = (const float*)d_in[3];
    const float* W_cq   = (const float*)d_in[4];
    const float* W_ckv  = (const float*)d_in[5];
    const float* W_sqkv = (const float*)d_in[6];
    const float* ffn_g  = (const float*)d_in[7];
    const float* ffn_b  = (const float*)d_in[8];
    const float* W1     = (const float*)d_in[9];
    const float* b1     = (const float*)d_in[10];
    const float* W2     = (const float*)d_in[11];
    const float* b2     = (const float*)d_in[12];
    float* out = (float*)d_out;

    char* ws = (char*)d_ws;
    unsigned short* wq_t   = (unsigned short*)(ws + (size_t)(0u)   * (1u << 20));  // 2MB
    unsigned short* wkv_t  = (unsigned short*)(ws + (size_t)(2u)   * (1u << 20));  // 1.5MB
    unsigned short* wqkv_t = (unsigned short*)(ws + (size_t)(4u)   * (1u << 20));  // 6MB
    unsigned short* w1_t   = (unsigned short*)(ws + (size_t)(10u)  * (1u << 20));  // 8MB
    unsigned short* w2_t   = (unsigned short*)(ws + (size_t)(18u)  * (1u << 20));  // 8MB
    unsigned short* featb  = (unsigned short*)(ws + (size_t)(26u)  * (1u << 20));  // 3MB
    unsigned short* t0     = (unsigned short*)(ws + (size_t)(29u)  * (1u << 20));  // 8MB
    float*          cross  = (float*)        (ws + (size_t)(37u)  * (1u << 20));   // 16MB
    unsigned short* qb     = (unsigned short*)(ws + (size_t)(53u)  * (1u << 20));  // 8MB
    unsigned short* kvb    = (unsigned short*)(ws + (size_t)(61u)  * (1u << 20));  // 16MB
    unsigned short* qkvb   = (unsigned short*)(ws + (size_t)(77u)  * (1u << 20));  // 24MB
    unsigned short* packb  = (unsigned short*)(ws + (size_t)(101u) * (1u << 20));  // 16MB
    unsigned short* h1     = (unsigned short*)(ws + (size_t)(53u)  * (1u << 20));  // 32MB (aliases q/kv/qkv, dead by FFN)

    // weights -> bf16 transposed [N,K]
    wconv_t<<<dim3(1024 / 32, 1024 / 32), 256, 0, stream>>>(W_cq,   wq_t,   1024, 1024);
    wconv_t<<<dim3(384 / 32,  2048 / 32), 256, 0, stream>>>(W_ckv,  wkv_t,  384,  2048);
    wconv_t<<<dim3(1024 / 32, 3072 / 32), 256, 0, stream>>>(W_sqkv, wqkv_t, 1024, 3072);
    wconv_t<<<dim3(1024 / 32, 4096 / 32), 256, 0, stream>>>(W1,     w1_t,   1024, 4096);
    wconv_t<<<dim3(4096 / 32, 1024 / 32), 256, 0, stream>>>(W2,     w2_t,   4096, 1024);
    fconv<<<dim3((4096 * 384 / 4) / 256), 256, 0, stream>>>(feat, featb, 4096 * 384 / 4);

    // ---- cross attention ----
    lnorm<<<4096, 256, 0, stream>>>(x, norm_g, norm_b, t0);
    gemm8<2, 2, 4, 2, 0, true ><<<512, 256, 0, stream>>>(t0,    wq_t,  qb,  nullptr, nullptr, 4096, 1024, 1024, 1024);
    gemm8<2, 2, 4, 4, 0, false><<<512, 256, 0, stream>>>(featb, wkv_t, kvb, nullptr, nullptr, 4096, 2048, 384,  0);
    kvpack<<<dim3(8, 32), 256, 0, stream>>>(kvb, 2048, 0, 1024, packb);
    attn<<<1024, 256, 0, stream>>>(qb, 1024, 0, packb, x, cross);

    // ---- self attention ----
    lnorm<<<4096, 256, 0, stream>>>(cross, norm_g, norm_b, t0);
    gemm256<0, true ><<<192, 512, 0, stream>>>(t0, wqkv_t, qkvb, nullptr, nullptr, 4096, 3072, 1024, 1024);
    kvpack<<<dim3(8, 32), 256, 0, stream>>>(qkvb, 3072, 1024, 2048, packb);
    attn<<<1024, 256, 0, stream>>>(qkvb, 3072, 0, packb, cross, out);

    // ---- FFN ----
    lnorm<<<4096, 256, 0, stream>>>(out, ffn_g, ffn_b, t0);
    gemm256<1, false><<<256, 512, 0, stream>>>(t0, w1_t, h1, b1, nullptr, 4096, 4096, 1024, 0);
    gemm8<2, 2, 4, 2, 2, false><<<512, 256, 0, stream>>>(h1, w2_t, out, b2, (const float*)out, 4096, 1024, 4096, 0);
}

// Round 11
// 321.388 us; speedup vs baseline: 1.1974x; 1.0252x over previous
//
#include <hip/hip_runtime.h>
#include <math.h>
#include <stdint.h>

typedef __attribute__((ext_vector_type(8)))  short   short8;
typedef __attribute__((ext_vector_type(4)))  short   short4v;
typedef __attribute__((ext_vector_type(8)))  __bf16  bf16x8;
typedef __attribute__((ext_vector_type(4)))  float   f32x4;
typedef __attribute__((ext_vector_type(16))) float   f32x16;

__device__ __forceinline__ unsigned short f2b(float f) {
    union { float f; unsigned u; } v; v.f = f;
    unsigned r = v.u + 0x7FFF + ((v.u >> 16) & 1);
    return (unsigned short)(r >> 16);
}

__device__ __forceinline__ float b2f(unsigned short u) {
    union { unsigned u; float f; } v; v.u = (unsigned)u << 16; return v.f;
}

__device__ __forceinline__ f32x4 mfma_bf16(bf16x8 a, bf16x8 b, f32x4 c) {
    return __builtin_amdgcn_mfma_f32_16x16x32_bf16(a, b, c, 0, 0, 0);
}

__device__ __forceinline__ f32x16 mfma32(bf16x8 a, bf16x8 b, f32x16 c) {
    return __builtin_amdgcn_mfma_f32_32x32x16_bf16(a, b, c, 0, 0, 0);
}

__device__ __forceinline__ unsigned cvt_pk_bf16(float lo, float hi) {
    unsigned r;
    asm volatile("v_cvt_pk_bf16_f32 %0, %1, %2" : "=v"(r) : "v"(lo), "v"(hi));
    return r;
}

__device__ __forceinline__ void gload_lds16(const unsigned short* g, unsigned short* l) {
    __builtin_amdgcn_global_load_lds(
        (const __attribute__((address_space(1))) void*)g,
        (__attribute__((address_space(3))) void*)l,
        16, 0, 0);
}

template <int N>
__device__ __forceinline__ void wait_vmcnt() {
    if constexpr (N == 0)       asm volatile("s_waitcnt vmcnt(0)" ::: "memory");
    else if constexpr (N == 4)  asm volatile("s_waitcnt vmcnt(4)" ::: "memory");
    else if constexpr (N == 6)  asm volatile("s_waitcnt vmcnt(6)" ::: "memory");
    else if constexpr (N == 8)  asm volatile("s_waitcnt vmcnt(8)" ::: "memory");
    else                        static_assert(N == 0 || N == 4 || N == 6 || N == 8, "add vmcnt case");
}

// 0.125 (d_head^-0.5) * log2(e): softmax computed in base-2 (exact rescale)
#define QSCALE 0.18033688011112042592f

// ---------------- weight transpose + f32->bf16 ----------------
__global__ __launch_bounds__(256) void wconv_t(const float* __restrict__ W,
                                               unsigned short* __restrict__ Wt,
                                               int K, int N) {
    __shared__ float tile[32][33];
    int bk = blockIdx.x * 32;
    int bn = blockIdx.y * 32;
    int tx = threadIdx.x & 31, ty = threadIdx.x >> 5;  // 32 x 8
#pragma unroll
    for (int i = 0; i < 4; ++i) {
        int r = ty + i * 8;
        tile[r][tx] = W[(size_t)(bk + r) * N + bn + tx];
    }
    __syncthreads();
#pragma unroll
    for (int i = 0; i < 4; ++i) {
        int r = ty + i * 8;
        Wt[(size_t)(bn + r) * K + bk + tx] = f2b(tile[tx][r]);
    }
}

// ---------------- f32 -> bf16 elementwise (x4) ----------------
__global__ __launch_bounds__(256) void fconv(const float* __restrict__ in,
                                             unsigned short* __restrict__ out, int n4) {
    int i = blockIdx.x * 256 + threadIdx.x;
    if (i >= n4) return;
    f32x4 v = ((const f32x4*)in)[i];
    short4v o;
    o.x = (short)f2b(v.x); o.y = (short)f2b(v.y);
    o.z = (short)f2b(v.z); o.w = (short)f2b(v.w);
    ((short4v*)out)[i] = o;
}

// ---------------- layernorm (C=1024), f32 in -> bf16 out ----------------
__global__ __launch_bounds__(256) void lnorm(const float* __restrict__ x,
                                             const float* __restrict__ g,
                                             const float* __restrict__ bta,
                                             unsigned short* __restrict__ out) {
    int row = blockIdx.x;
    const f32x4* xr = (const f32x4*)(x + (size_t)row * 1024);
    int t = threadIdx.x;
    f32x4 v = xr[t];
    float s  = v.x + v.y + v.z + v.w;
    float s2 = v.x * v.x + v.y * v.y + v.z * v.z + v.w * v.w;
#pragma unroll
    for (int m = 1; m < 64; m <<= 1) {
        s  += __shfl_xor(s, m);
        s2 += __shfl_xor(s2, m);
    }
    __shared__ float rs[8];
    int w = t >> 6;
    if ((t & 63) == 0) { rs[w] = s; rs[4 + w] = s2; }
    __syncthreads();
    s  = rs[0] + rs[1] + rs[2] + rs[3];
    s2 = rs[4] + rs[5] + rs[6] + rs[7];
    float mean = s * (1.0f / 1024.0f);
    float var  = s2 * (1.0f / 1024.0f) - mean * mean;
    float rstd = rsqrtf(var + 1e-5f);
    f32x4 gv = ((const f32x4*)g)[t];
    f32x4 bv = ((const f32x4*)bta)[t];
    short4v o;
    o.x = (short)f2b((v.x - mean) * rstd * gv.x + bv.x);
    o.y = (short)f2b((v.y - mean) * rstd * gv.y + bv.y);
    o.z = (short)f2b((v.z - mean) * rstd * gv.z + bv.z);
    o.w = (short)f2b((v.w - mean) * rstd * gv.w + bv.w);
    ((short4v*)(out + (size_t)row * 1024))[t] = o;
}

// ---------------- pipelined GEMM: A[M,K] x Bt[N,K] -> C[M,N], BK=64 ----------------
template <int WM, int WN, int MI, int NI, int EPI, bool SCQ>
__global__ __launch_bounds__(WM * WN * 64, 2)
void gemm8(const unsigned short* __restrict__ A,
           const unsigned short* __restrict__ Bt,
           void* __restrict__ C,
           const float* __restrict__ bias,
           const float* __restrict__ resid,
           int M, int N, int K, int scale_cols) {
    constexpr int BM = WM * MI * 16;
    constexpr int BN = WN * NI * 16;
    constexpr int THREADS = WM * WN * 64;
    constexpr int ROWS = THREADS / 8;          // rows per stage instr
    constexpr int IA = BM / ROWS;              // stage instrs for A
    constexpr int IB = BN / ROWS;

    // bijective XCD swizzle (all grids are multiples of 8), m-major per XCD
    const int nwg = gridDim.x;
    const int nby = N / BN;
    int flat = blockIdx.x;
    int wk = (flat & 7) * (nwg >> 3) + (flat >> 3);
    const int m0 = (wk / nby) * BM;
    const int n0 = (wk % nby) * BN;

    __shared__ unsigned short As[2][BM * 64];
    __shared__ unsigned short Bs[2][BN * 64];

    const int tid  = threadIdx.x;
    const int lane = tid & 63;
    const int wid  = tid >> 6;
    const int wm = wid / WN, wn = wid % WN;
    const int l15 = lane & 15, q4 = lane >> 4, xw = lane & 7;

    const int sr = tid >> 3;                    // stage row within group
    const int sg = (tid & 7) ^ (sr & 7);        // swizzled source granule

    const unsigned short* ag = A  + (size_t)(m0 + sr) * K + sg * 8;
    const unsigned short* bg = Bt + (size_t)(n0 + sr) * K + sg * 8;

    f32x4 acc[MI][NI] = {};

    auto STAGE = [&](int d, int t) {
        const int k0 = t * 64;
#pragma unroll
        for (int i = 0; i < IA; ++i)
            gload_lds16(ag + (size_t)(i * ROWS) * K + k0, &As[d][i * ROWS * 64 + tid * 8]);
#pragma unroll
        for (int i = 0; i < IB; ++i)
            gload_lds16(bg + (size_t)(i * ROWS) * K + k0, &Bs[d][i * ROWS * 64 + tid * 8]);
    };

    const int NT = K >> 6;
    STAGE(0, 0);

    for (int t = 0; t < NT; ++t) {
        const int c = t & 1;
        if (t + 1 < NT) STAGE(c ^ 1, t + 1);
        __builtin_amdgcn_sched_barrier(0);
        if (t + 1 < NT) wait_vmcnt<IA + IB>();
        else            wait_vmcnt<0>();
        __builtin_amdgcn_s_barrier();
        __builtin_amdgcn_sched_barrier(0);
#pragma unroll
        for (int h = 0; h < 2; ++h) {
            bf16x8 a[MI], b[NI];
            const int gsl = h * 4 + q4;         // granule before swizzle
#pragma unroll
            for (int mi = 0; mi < MI; ++mi)
                a[mi] = *(const bf16x8*)&As[c][(wm * MI * 16 + mi * 16 + l15) * 64 + ((gsl ^ xw) << 3)];
#pragma unroll
            for (int ni = 0; ni < NI; ++ni)
                b[ni] = *(const bf16x8*)&Bs[c][(wn * NI * 16 + ni * 16 + l15) * 64 + ((gsl ^ xw) << 3)];
            __builtin_amdgcn_s_setprio(1);
#pragma unroll
            for (int mi = 0; mi < MI; ++mi)
#pragma unroll
                for (int ni = 0; ni < NI; ++ni)
                    acc[mi][ni] = mfma_bf16(a[mi], b[ni], acc[mi][ni]);
            __builtin_amdgcn_s_setprio(0);
        }
        __builtin_amdgcn_sched_barrier(0);
        __builtin_amdgcn_s_barrier();
    }

    // epilogue
    const int rb = m0 + wm * MI * 16 + q4 * 4;
    const int cb = n0 + wn * NI * 16 + l15;
    float bv[NI];
    if (EPI >= 1) {
#pragma unroll
        for (int ni = 0; ni < NI; ++ni) bv[ni] = bias[cb + ni * 16];
    }
#pragma unroll
    for (int mi = 0; mi < MI; ++mi) {
#pragma unroll
        for (int r = 0; r < 4; ++r) {
            const int row = rb + mi * 16 + r;
#pragma unroll
            for (int ni = 0; ni < NI; ++ni) {
                const int col = cb + ni * 16;
                float v = acc[mi][ni][r];
                if (EPI == 0) {
                    if (SCQ && col < scale_cols) v *= QSCALE;
                    ((unsigned short*)C)[(size_t)row * N + col] = f2b(v);
                } else if (EPI == 1) {
                    v += bv[ni];
                    v = 0.5f * v * (1.0f + erff(v * 0.70710678118f));
                    ((unsigned short*)C)[(size_t)row * N + col] = f2b(v);
                } else {
                    v += bv[ni] + resid[(size_t)row * N + col];
                    ((float*)C)[(size_t)row * N + col] = v;
                }
            }
        }
    }
}

// ---------------- 256^2 8-wave GEMM (4 phases/K-tile), optional split-K ----------------
// EPI: 0 = bf16 out (+QSCALE), 1 = bf16 out +bias +GELU, 3 = bf16 raw partial
// (split-K: partial ks goes to (ks&2 ? ph1 : ph0) + (ks&1)*M*N).
template <int EPI, bool SCQ, int KSPLIT>
__global__ __launch_bounds__(512, 2)
void gemm256(const unsigned short* __restrict__ A,
             const unsigned short* __restrict__ Bt,
             void* __restrict__ C,
             const float* __restrict__ bias,
             unsigned short* __restrict__ ph0,
             unsigned short* __restrict__ ph1,
             int M, int N, int lda, int ldb, int klen, int scale_cols) {
    const int nby = N / 256;
    const int nmn = (M / 256) * nby;
    const int nwg = gridDim.x;
    int flat = blockIdx.x;
    int wk = (flat & 7) * (nwg >> 3) + (flat >> 3);
    int ks = 0;
    if constexpr (KSPLIT > 1) { ks = wk / nmn; wk -= ks * nmn; }
    const int m0 = (wk / nby) * 256;
    const int n0 = (wk % nby) * 256;
    const int koff = ks * klen;

    __shared__ unsigned short As[2][256 * 64];
    __shared__ unsigned short Bs[2][256 * 64];

    const int tid  = threadIdx.x;
    const int lane = tid & 63;
    const int wid  = tid >> 6;                 // 0..7
    const int wm = wid >> 2, wn = wid & 3;     // 2 x 4 waves
    const int l15 = lane & 15, q4 = lane >> 4, xw = lane & 7;

    const int sr = tid >> 3;                   // 0..63
    const int sg = (tid & 7) ^ (sr & 7);       // swizzled source granule

    const unsigned short* ag = A  + (size_t)(m0 + sr) * lda + koff + sg * 8;
    const unsigned short* bg = Bt + (size_t)(n0 + sr) * ldb + koff + sg * 8;

    f32x4 acc[8][4] = {};

#define SA256(d, t, i) gload_lds16(ag + (size_t)((i) * 64) * lda + (t) * 64, &As[d][(i) * 4096 + tid * 8])
#define SB256(d, t, i) gload_lds16(bg + (size_t)((i) * 64) * ldb + (t) * 64, &Bs[d][(i) * 4096 + tid * 8])

    const int NT = klen >> 6;
#pragma unroll
    for (int i = 0; i < 4; ++i) { SA256(0, 0, i); SB256(0, 0, i); }
    wait_vmcnt<0>();
    __builtin_amdgcn_s_barrier();

    for (int t = 0; t < NT; ++t) {
        const int c = t & 1;
        const bool pf = (t + 1 < NT);
        bf16x8 breg[4];
#pragma unroll
        for (int p = 0; p < 4; ++p) {
            const int h = p >> 1, mh = p & 1;
            const int col = ((h * 4 + q4) ^ xw) << 3;
            if ((p & 1) == 0) {
#pragma unroll
                for (int ni = 0; ni < 4; ++ni)
                    breg[ni] = *(const bf16x8*)&Bs[c][(wn * 64 + ni * 16 + l15) * 64 + col];
            }
            bf16x8 a[4];
#pragma unroll
            for (int mi = 0; mi < 4; ++mi)
                a[mi] = *(const bf16x8*)&As[c][(wm * 128 + mh * 64 + mi * 16 + l15) * 64 + col];
            if (pf) {
                if (p == 0)      { SA256(c ^ 1, t + 1, 0); SB256(c ^ 1, t + 1, 0); SA256(c ^ 1, t + 1, 1); }
                else if (p == 1) { SB256(c ^ 1, t + 1, 1); SA256(c ^ 1, t + 1, 2); SB256(c ^ 1, t + 1, 2); }
                else if (p == 2) { SA256(c ^ 1, t + 1, 3); SB256(c ^ 1, t + 1, 3); }
            }
            __builtin_amdgcn_sched_barrier(0);
            asm volatile("s_waitcnt lgkmcnt(0)" ::: "memory");
            __builtin_amdgcn_sched_barrier(0);
            __builtin_amdgcn_s_setprio(1);
#pragma unroll
            for (int mi = 0; mi < 4; ++mi)
#pragma unroll
                for (int ni = 0; ni < 4; ++ni)
                    acc[mh * 4 + mi][ni] = mfma_bf16(a[mi], breg[ni], acc[mh * 4 + mi][ni]);
            __builtin_amdgcn_s_setprio(0);
            __builtin_amdgcn_sched_barrier(0);
            if (p == 3) wait_vmcnt<0>();
            __builtin_amdgcn_s_barrier();
        }
    }
#undef SA256
#undef SB256

    const int rb = m0 + wm * 128 + q4 * 4;
    const int cb = n0 + wn * 64 + l15;
    float bv[4];
    if (EPI == 1) {
#pragma unroll
        for (int ni = 0; ni < 4; ++ni) bv[ni] = bias[cb + ni * 16];
    }
    unsigned short* pb = nullptr;
    if (EPI == 3) pb = ((ks & 2) ? ph1 : ph0) + (size_t)(ks & 1) * ((size_t)M * N);
#pragma unroll
    for (int ai = 0; ai < 8; ++ai) {
#pragma unroll
        for (int r = 0; r < 4; ++r) {
            const int row = rb + ai * 16 + r;
#pragma unroll
            for (int ni = 0; ni < 4; ++ni) {
                const int col = cb + ni * 16;
                float v = acc[ai][ni][r];
                if (EPI == 0) {
                    if (SCQ && col < scale_cols) v *= QSCALE;
                    ((unsigned short*)C)[(size_t)row * N + col] = f2b(v);
                } else if (EPI == 1) {
                    v += bv[ni];
                    v = 0.5f * v * (1.0f + erff(v * 0.70710678118f));
                    ((unsigned short*)C)[(size_t)row * N + col] = f2b(v);
                } else {
                    pb[(size_t)row * N + col] = f2b(v);
                }
            }
        }
    }
}

// ---------------- split-K merge: out += p0+p1+p2+p3 + bias ----------------
__global__ __launch_bounds__(256) void kmerge(const unsigned short* __restrict__ p01,
                                              const unsigned short* __restrict__ p23,
                                              const float* __restrict__ bias,
                                              float* __restrict__ out) {
    const size_t i4 = (size_t)blockIdx.x * 256 + threadIdx.x;  // f32x4 index, 1M total
    const size_t e = i4 * 4;
    const int col4 = (int)(e & 1023);
    f32x4 acc = *(const f32x4*)&bias[col4];
    const size_t MN = (size_t)4096 * 1024;
#pragma unroll
    for (int k = 0; k < 2; ++k) {
        short4v a = *(const short4v*)&p01[k * MN + e];
        short4v b = *(const short4v*)&p23[k * MN + e];
        acc.x += b2f((unsigned short)a.x) + b2f((unsigned short)b.x);
        acc.y += b2f((unsigned short)a.y) + b2f((unsigned short)b.y);
        acc.z += b2f((unsigned short)a.z) + b2f((unsigned short)b.z);
        acc.w += b2f((unsigned short)a.w) + b2f((unsigned short)b.w);
    }
    f32x4 o = *(const f32x4*)&out[e];
    o.x += acc.x; o.y += acc.y; o.z += acc.z; o.w += acc.w;
    *(f32x4*)&out[e] = o;
}

// ---------------- K/V fragment pre-pack ----------------
__global__ __launch_bounds__(256) void kvpack(const unsigned short* __restrict__ src,
                                              int stride, int k_off, int v_off,
                                              unsigned short* __restrict__ pack) {
    const int oct = blockIdx.x;      // 0..7 (8 k-tiles each)
    const int bh  = blockIdx.y;      // 0..31
    const int b = bh >> 4, h = bh & 15;
    const int tid = threadIdx.x;
    const int lane = tid & 63;
    const int sl = tid >> 6;         // 0..3
    const int l31 = lane & 31, l5 = lane >> 5;
    __shared__ unsigned short Kl[32 * 64], Vl[32 * 64];
    const int r = tid >> 3, c8 = (tid & 7) * 8;
    for (int t8 = 0; t8 < 8; ++t8) {
        const int kt = oct * 8 + t8;
        const int kb = kt * 32;
        *(short8*)&Kl[r * 64 + c8] = *(const short8*)&src[(size_t)(b * 2048 + kb + r) * stride + k_off + h * 64 + c8];
        *(short8*)&Vl[r * 64 + c8] = *(const short8*)&src[(size_t)(b * 2048 + kb + r) * stride + v_off + h * 64 + c8];
        __syncthreads();
        unsigned short* o = pack + (size_t)bh * 262144 + (size_t)kt * 4096;
        *(short8*)&o[sl * 512 + lane * 8] = *(const short8*)&Kl[l31 * 64 + sl * 16 + l5 * 8];
        {
            const int dh = sl >> 1, c2 = sl & 1;
            short8 vv;
#pragma unroll
            for (int j = 0; j < 8; ++j)
                vv[j] = (short)Vl[(c2 * 16 + l5 * 8 + j) * 64 + dh * 32 + l31];
            *(short8*)&o[(4 + sl) * 512 + lane * 8] = vv;
        }
        __syncthreads();
    }
}

// ---------------- flash attention v8: no-max softmax, k-split, 4 waves/block ----------------
__global__ __launch_bounds__(256) void attn(const unsigned short* __restrict__ Q, int q_stride, int q_off,
                                            const unsigned short* __restrict__ pack,
                                            const float* __restrict__ res,
                                            float* __restrict__ out) {
    const int bid = blockIdx.x;            // 0..1023
    const int slot = bid >> 3;             // 0..127
    const int bh = (bid & 7) * 4 + (slot >> 5);
    const int qt = slot & 31;              // 64 q-rows per block
    const int b = bh >> 4, h = bh & 15;
    const int tid = threadIdx.x;
    const int lane = tid & 63, w = tid >> 6;   // w in 0..3
    const int qg = w >> 1, ks = w & 1;
    const int l31 = lane & 31, l5 = lane >> 5;

    __shared__ unsigned short lds[2][8192];    // 16KB per buffer; reused for merge

    const int q0 = qt * 64 + qg * 32;

    const unsigned short* qp = Q + (size_t)(b * 2048 + q0 + l31) * q_stride + q_off + h * 64 + l5 * 8;
    bf16x8 qf[4];
#pragma unroll
    for (int i = 0; i < 4; ++i) qf[i] = *(const bf16x8*)&qp[i * 16];

    const unsigned short* pkb = pack + (size_t)bh * 262144;

    f32x16 oacc[2] = {};
    f32x16 lacc = {};

    auto STAGE = [&](int d, int t) {
        const unsigned short* s = pkb + (size_t)t * 8192;
#pragma unroll
        for (int i = 0; i < 4; ++i) {
            const int ch = i * 4 + w;
            gload_lds16(s + ch * 512 + lane * 8, &lds[d][ch * 512 + lane * 8]);
        }
    };

    STAGE(0, 0);

    for (int t = 0; t < 32; ++t) {
        const int cur = t & 1;
        if (t + 1 < 32) STAGE(cur ^ 1, t + 1);
        __builtin_amdgcn_sched_barrier(0);
        if (t + 1 < 32) wait_vmcnt<4>();
        else            wait_vmcnt<0>();
        __builtin_amdgcn_s_barrier();
        __builtin_amdgcn_sched_barrier(0);

        const unsigned short* L = &lds[cur][ks * 4096 + lane * 8];

        bf16x8 kf[4];
#pragma unroll
        for (int i = 0; i < 4; ++i) kf[i] = *(const bf16x8*)&L[i * 512];

        f32x16 s = {};
        __builtin_amdgcn_s_setprio(1);
#pragma unroll
        for (int i = 0; i < 4; ++i) s = mfma32(kf[i], qf[i], s);
        __builtin_amdgcn_s_setprio(0);

        bf16x8 vf[2][2];
#pragma unroll
        for (int dh = 0; dh < 2; ++dh)
#pragma unroll
            for (int c2 = 0; c2 < 2; ++c2)
                vf[dh][c2] = *(const bf16x8*)&L[(4 + dh * 2 + c2) * 512];

        float p[16];
#pragma unroll
        for (int r = 0; r < 16; ++r) p[r] = __builtin_amdgcn_exp2f(s[r]);
#pragma unroll
        for (int r = 0; r < 16; ++r) lacc[r] += p[r];

        bf16x8 pf[2];
#pragma unroll
        for (int c = 0; c < 2; ++c) {
            unsigned a0 = cvt_pk_bf16(p[8 * c + 0], p[8 * c + 1]);
            unsigned a1 = cvt_pk_bf16(p[8 * c + 4], p[8 * c + 5]);
            unsigned b0 = cvt_pk_bf16(p[8 * c + 2], p[8 * c + 3]);
            unsigned b1 = cvt_pk_bf16(p[8 * c + 6], p[8 * c + 7]);
            asm volatile("v_permlane32_swap_b32 %0, %1" : "+v"(a0), "+v"(a1));
            asm volatile("v_permlane32_swap_b32 %0, %1" : "+v"(b0), "+v"(b1));
            union { unsigned u[4]; bf16x8 v; } pu;
            pu.u[0] = a0; pu.u[1] = b0; pu.u[2] = a1; pu.u[3] = b1;
            pf[c] = pu.v;
        }

        __builtin_amdgcn_s_setprio(1);
#pragma unroll
        for (int dh = 0; dh < 2; ++dh)
#pragma unroll
            for (int c2 = 0; c2 < 2; ++c2)
                oacc[dh] = mfma32(vf[dh][c2], pf[c2], oacc[dh]);
        __builtin_amdgcn_s_setprio(0);

        __builtin_amdgcn_s_barrier();
    }

    float lsum[16];
#pragma unroll
    for (int r = 0; r < 16; ++r) lsum[r] = lacc[r];
#pragma unroll
    for (int off = 8; off >= 1; off >>= 1)
#pragma unroll
        for (int r = 0; r < off; ++r) lsum[r] += lsum[r + off];
    float lh = lsum[0] + __shfl_xor(lsum[0], 32);

    float* mb = (float*)&lds[qg][0];
    if (ks == 1) {
#pragma unroll
        for (int dh = 0; dh < 2; ++dh)
#pragma unroll
            for (int r = 0; r < 16; ++r)
                mb[lane * 33 + dh * 16 + r] = oacc[dh][r];
        mb[lane * 33 + 32] = lh;
    }
    __syncthreads();
    if (ks == 0) {
#pragma unroll
        for (int dh = 0; dh < 2; ++dh)
#pragma unroll
            for (int r = 0; r < 16; ++r)
                oacc[dh][r] += mb[lane * 33 + dh * 16 + r];
        const float l = lh + mb[lane * 33 + 32];

        const float inv = 1.0f / l;
        const size_t rowoff = (size_t)(b * 2048 + q0 + l31) * 1024 + h * 64;
#pragma unroll
        for (int dh = 0; dh < 2; ++dh) {
#pragma unroll
            for (int g = 0; g < 4; ++g) {
                const int col = dh * 32 + g * 8 + l5 * 4;
                f32x4 rv = *(const f32x4*)&res[rowoff + col];
                f32x4 ov;
#pragma unroll
                for (int r = 0; r < 4; ++r) ov[r] = oacc[dh][g * 4 + r] * inv + rv[r];
                *(f32x4*)&out[rowoff + col] = ov;
            }
        }
    }
}

// ---------------- host ----------------
extern "C" void kernel_launch(void* const* d_in, const int* in_sizes, int n_in,
                              void* d_out, int out_size, void* d_ws, size_t ws_size,
                              hipStream_t stream) {
    const float* x      = (const float*)d_in[0];
    const float* feat   = (const float*)d_in[1];
    const float* norm_g = (const float*)d_in[2];
    const float* norm_b = (const float*)d_in[3];
    const float* W_cq   = (const float*)d_in[4];
    const float* W_ckv  = (const float*)d_in[5];
    const float* W_sqkv = (const float*)d_in[6];
    const float* ffn_g  = (const float*)d_in[7];
    const float* ffn_b  = (const float*)d_in[8];
    const float* W1     = (const float*)d_in[9];
    const float* b1     = (const float*)d_in[10];
    const float* W2     = (const float*)d_in[11];
    const float* b2     = (const float*)d_in[12];
    float* out = (float*)d_out;

    char* ws = (char*)d_ws;
    unsigned short* wq_t   = (unsigned short*)(ws + (size_t)(0u)   * (1u << 20));  // 2MB
    unsigned short* wkv_t  = (unsigned short*)(ws + (size_t)(2u)   * (1u << 20));  // 1.5MB
    unsigned short* wqkv_t = (unsigned short*)(ws + (size_t)(4u)   * (1u << 20));  // 6MB
    unsigned short* w1_t   = (unsigned short*)(ws + (size_t)(10u)  * (1u << 20));  // 8MB
    unsigned short* w2_t   = (unsigned short*)(ws + (size_t)(18u)  * (1u << 20));  // 8MB
    unsigned short* featb  = (unsigned short*)(ws + (size_t)(26u)  * (1u << 20));  // 3MB
    unsigned short* t0     = (unsigned short*)(ws + (size_t)(29u)  * (1u << 20));  // 8MB
    float*          cross  = (float*)        (ws + (size_t)(37u)  * (1u << 20));   // 16MB (dead by FFN -> part01)
    unsigned short* qb     = (unsigned short*)(ws + (size_t)(53u)  * (1u << 20));  // 8MB
    unsigned short* kvb    = (unsigned short*)(ws + (size_t)(61u)  * (1u << 20));  // 16MB
    unsigned short* qkvb   = (unsigned short*)(ws + (size_t)(77u)  * (1u << 20));  // 24MB
    unsigned short* packb  = (unsigned short*)(ws + (size_t)(101u) * (1u << 20));  // 16MB (dead by FFN -> part23)
    unsigned short* h1     = (unsigned short*)(ws + (size_t)(53u)  * (1u << 20));  // 32MB (aliases q/kv/qkv, dead by FFN)
    unsigned short* part01 = (unsigned short*)(ws + (size_t)(37u)  * (1u << 20));  // 16MB over cross
    unsigned short* part23 = (unsigned short*)(ws + (size_t)(101u) * (1u << 20));  // 16MB over packb

    // weights -> bf16 transposed [N,K]
    wconv_t<<<dim3(1024 / 32, 1024 / 32), 256, 0, stream>>>(W_cq,   wq_t,   1024, 1024);
    wconv_t<<<dim3(384 / 32,  2048 / 32), 256, 0, stream>>>(W_ckv,  wkv_t,  384,  2048);
    wconv_t<<<dim3(1024 / 32, 3072 / 32), 256, 0, stream>>>(W_sqkv, wqkv_t, 1024, 3072);
    wconv_t<<<dim3(1024 / 32, 4096 / 32), 256, 0, stream>>>(W1,     w1_t,   1024, 4096);
    wconv_t<<<dim3(4096 / 32, 1024 / 32), 256, 0, stream>>>(W2,     w2_t,   4096, 1024);
    fconv<<<dim3((4096 * 384 / 4) / 256), 256, 0, stream>>>(feat, featb, 4096 * 384 / 4);

    // ---- cross attention ----
    lnorm<<<4096, 256, 0, stream>>>(x, norm_g, norm_b, t0);
    gemm8<2, 2, 4, 2, 0, true ><<<512, 256, 0, stream>>>(t0,    wq_t,  qb,  nullptr, nullptr, 4096, 1024, 1024, 1024);
    gemm8<2, 2, 4, 4, 0, false><<<512, 256, 0, stream>>>(featb, wkv_t, kvb, nullptr, nullptr, 4096, 2048, 384,  0);
    kvpack<<<dim3(8, 32), 256, 0, stream>>>(kvb, 2048, 0, 1024, packb);
    attn<<<1024, 256, 0, stream>>>(qb, 1024, 0, packb, x, cross);

    // ---- self attention ----
    lnorm<<<4096, 256, 0, stream>>>(cross, norm_g, norm_b, t0);
    gemm256<0, true , 1><<<192, 512, 0, stream>>>(t0, wqkv_t, qkvb, nullptr, nullptr, nullptr, 4096, 3072, 1024, 1024, 1024, 1024);
    kvpack<<<dim3(8, 32), 256, 0, stream>>>(qkvb, 3072, 1024, 2048, packb);
    attn<<<1024, 256, 0, stream>>>(qkvb, 3072, 0, packb, cross, out);

    // ---- FFN ----
    lnorm<<<4096, 256, 0, stream>>>(out, ffn_g, ffn_b, t0);
    // W1: 4096x4096 @ K=1024, 256^2 8-phase -> 256 blocks, GELU epilogue
    gemm256<1, false, 1><<<256, 512, 0, stream>>>(t0, w1_t, h1, b1, nullptr, nullptr, 4096, 4096, 1024, 1024, 1024, 0);
    // W2: 4096x1024 @ K=4096 split-K=4 (each 256^2 x K=1024) -> 256 blocks, bf16 partials
    gemm256<3, false, 4><<<256, 512, 0, stream>>>(h1, w2_t, nullptr, nullptr, part01, part23, 4096, 1024, 4096, 4096, 1024, 0);
    // merge: out += p0+p1+p2+p3 + b2 (out already holds self_tok residual)
    kmerge<<<4096, 256, 0, stream>>>(part01, part23, b2, out);
}